// Round 1
// baseline (1271.689 us; speedup 1.0000x reference)
//
#include <hip/hip_runtime.h>

#define N_NODES 100000
#define N_EDGES 3200000
constexpr int F = 128;
constexpr int CAP = 128;  // padded-CSR capacity per node; P(deg>128) ~ e^-81

// ---------------- dense matmul: out[n,H] = act(A[n,128] @ W[128,H] + b) ----------
// 4 rows x 4 cols per thread, float4 loads, no LDS (W rows broadcast via L1).
template<int H, bool RELU, bool BIAS>
__global__ __launch_bounds__(256) void mm_kernel(const float* __restrict__ A,
                                                 const float* __restrict__ W,
                                                 const float* __restrict__ bias,
                                                 float* __restrict__ out) {
    constexpr int CG  = H / 4;        // col groups of 4
    constexpr int RS  = 256 / CG;     // row subgroups per block
    constexpr int RPB = RS * 4;       // rows per block
    const int tid  = threadIdx.x;
    const int c4   = tid % CG;
    const int rs   = tid / CG;
    const int row0 = blockIdx.x * RPB + rs * 4;

    float acc[4][4] = {};
    const float4* Wp = reinterpret_cast<const float4*>(W);

#pragma unroll 4
    for (int k4 = 0; k4 < F / 4; ++k4) {
        float4 a[4], w[4];
#pragma unroll
        for (int r = 0; r < 4; ++r)
            a[r] = reinterpret_cast<const float4*>(A + (size_t)(row0 + r) * F)[k4];
#pragma unroll
        for (int j = 0; j < 4; ++j)
            w[j] = Wp[(size_t)(k4 * 4 + j) * CG + c4];
#pragma unroll
        for (int r = 0; r < 4; ++r) {
#pragma unroll
            for (int j = 0; j < 4; ++j) {
                const float av = (j == 0) ? a[r].x : (j == 1) ? a[r].y : (j == 2) ? a[r].z : a[r].w;
                acc[r][0] = fmaf(av, w[j].x, acc[r][0]);
                acc[r][1] = fmaf(av, w[j].y, acc[r][1]);
                acc[r][2] = fmaf(av, w[j].z, acc[r][2]);
                acc[r][3] = fmaf(av, w[j].w, acc[r][3]);
            }
        }
    }

    float4 b4 = {0.f, 0.f, 0.f, 0.f};
    if (BIAS) b4 = reinterpret_cast<const float4*>(bias)[c4];
#pragma unroll
    for (int r = 0; r < 4; ++r) {
        float4 v;
        v.x = acc[r][0] + b4.x;
        v.y = acc[r][1] + b4.y;
        v.z = acc[r][2] + b4.z;
        v.w = acc[r][3] + b4.w;
        if (RELU) {
            v.x = fmaxf(v.x, 0.f); v.y = fmaxf(v.y, 0.f);
            v.z = fmaxf(v.z, 0.f); v.w = fmaxf(v.w, 0.f);
        }
        reinterpret_cast<float4*>(out + (size_t)(row0 + r) * H)[c4] = v;
    }
}

// ---------------- graph prep ----------------
__global__ __launch_bounds__(256) void deg_kernel(const int* __restrict__ dst,
                                                  int* __restrict__ degi, int E) {
    int e = blockIdx.x * 256 + threadIdx.x;
    if (e < E) atomicAdd(&degi[dst[e]], 1);
}

__global__ __launch_bounds__(256) void dinv_kernel(const int* __restrict__ degi,
                                                   float* __restrict__ dinv, int n) {
    int i = blockIdx.x * 256 + threadIdx.x;
    if (i < n) dinv[i] = rsqrtf(1.0f + (float)degi[i]);
}

__global__ __launch_bounds__(256) void fill_kernel(const int* __restrict__ src,
                                                   const int* __restrict__ dst,
                                                   int* __restrict__ cursor,
                                                   int* __restrict__ csr, int E) {
    int e = blockIdx.x * 256 + threadIdx.x;
    if (e < E) {
        int d = dst[e];
        int p = atomicAdd(&cursor[d], 1);
        if (p < CAP) csr[(size_t)d * CAP + p] = src[e];
    }
}

// ---------------- aggregation: h2 = relu(sum_in xw[src]*coef + xw*dinv^2 + b) ----
// one wave per node, 64 lanes x float2 = 128 features
__global__ __launch_bounds__(256) void agg_kernel(const float* __restrict__ xw,
                                                  const int* __restrict__ csr,
                                                  const int* __restrict__ degi,
                                                  const float* __restrict__ dinv,
                                                  const float* __restrict__ bg,
                                                  float* __restrict__ h2) {
    const int wave = threadIdx.x >> 6;
    const int lane = threadIdx.x & 63;
    const int node = blockIdx.x * 4 + wave;
    if (node >= N_NODES) return;

    int d = degi[node];
    if (d > CAP) d = CAP;
    const float dv = dinv[node];
    const int* row = csr + (size_t)node * CAP;

    float2 acc = {0.f, 0.f};
    for (int j = 0; j < d; ++j) {
        int s = __builtin_amdgcn_readfirstlane(row[j]);
        float c = dinv[s] * dv;
        float2 v = reinterpret_cast<const float2*>(xw + (size_t)s * F)[lane];
        acc.x = fmaf(v.x, c, acc.x);
        acc.y = fmaf(v.y, c, acc.y);
    }
    // self-loop
    const float sc = dv * dv;
    float2 vs = reinterpret_cast<const float2*>(xw + (size_t)node * F)[lane];
    acc.x = fmaf(vs.x, sc, acc.x);
    acc.y = fmaf(vs.y, sc, acc.y);
    // bias + relu
    acc.x = fmaxf(acc.x + bg[lane * 2 + 0], 0.f);
    acc.y = fmaxf(acc.y + bg[lane * 2 + 1], 0.f);
    reinterpret_cast<float2*>(h2 + (size_t)node * F)[lane] = acc;
}

// ---------------- final layer: q[n,10] = hq[n,256] @ W2[256,10] + b2 -------------
// one wave per node; lane holds 4 k-values; 10 butterfly reductions
__global__ __launch_bounds__(256) void qout_kernel(const float* __restrict__ hq,
                                                   const float* __restrict__ W2,
                                                   const float* __restrict__ b2,
                                                   float* __restrict__ q) {
    const int wave = threadIdx.x >> 6;
    const int lane = threadIdx.x & 63;
    const int node = blockIdx.x * 4 + wave;
    if (node >= N_NODES) return;

    float4 hv = reinterpret_cast<const float4*>(hq + (size_t)node * 256)[lane];
    const float* w = W2 + (size_t)lane * 4 * 10;

    float acc[10];
#pragma unroll
    for (int o = 0; o < 10; ++o) {
        acc[o] = hv.x * w[o] + hv.y * w[10 + o] + hv.z * w[20 + o] + hv.w * w[30 + o];
    }
#pragma unroll
    for (int o = 0; o < 10; ++o) {
#pragma unroll
        for (int off = 32; off > 0; off >>= 1)
            acc[o] += __shfl_xor(acc[o], off, 64);
    }
    if (lane < 10) {
        float v = 0.f;
#pragma unroll
        for (int o = 0; o < 10; ++o)
            if (lane == o) v = acc[o];
        q[(size_t)node * 10 + lane] = v + b2[lane];
    }
}

extern "C" void kernel_launch(void* const* d_in, const int* in_sizes, int n_in,
                              void* d_out, int out_size, void* d_ws, size_t ws_size,
                              hipStream_t stream) {
    const float* x     = (const float*)d_in[0];
    const int*   ei    = (const int*)d_in[1];
    const float* W_enc = (const float*)d_in[2];
    const float* b_enc = (const float*)d_in[3];
    const float* W_gcn = (const float*)d_in[4];
    const float* b_gcn = (const float*)d_in[5];
    const float* W1    = (const float*)d_in[6];
    const float* b1    = (const float*)d_in[7];
    const float* W2    = (const float*)d_in[8];
    const float* b2    = (const float*)d_in[9];
    float* q = (float*)d_out;

    const int E = in_sizes[1] / 2;
    const int* srcv = ei;
    const int* dstv = ei + E;

    // workspace layout (bytes); h2 overlays h, hq overlays xw+csr
    char* ws = (char*)d_ws;
    const size_t NF = (size_t)N_NODES * F * sizeof(float);   // 51,200,000
    float* h    = (float*)(ws);
    float* xw   = (float*)(ws + NF);
    int*   csr  = (int*)  (ws + 2 * NF);
    float* hq   = (float*)(ws + NF);                          // 102.4 MB overlay
    float* h2   = h;
    int*   degi = (int*)  (ws + 3 * NF);
    int*   cur  = (int*)  (ws + 3 * NF + 512 * 1024);
    float* dinv = (float*)(ws + 3 * NF + 1024 * 1024);
    // total <= 3*NF + 1.5MB  ~= 155 MB

    hipMemsetAsync(degi, 0, N_NODES * sizeof(int), stream);
    hipMemsetAsync(cur,  0, N_NODES * sizeof(int), stream);

    // 1) h = relu(x @ W_enc + b_enc)
    mm_kernel<128, true, true><<<N_NODES / 32, 256, 0, stream>>>(x, W_enc, b_enc, h);
    // graph degree (overlap-friendly ordering)
    deg_kernel<<<(E + 255) / 256, 256, 0, stream>>>(dstv, degi, E);
    // 2) xw = h @ W_gcn
    mm_kernel<128, false, false><<<N_NODES / 32, 256, 0, stream>>>(h, W_gcn, nullptr, xw);
    dinv_kernel<<<(N_NODES + 255) / 256, 256, 0, stream>>>(degi, dinv, N_NODES);
    fill_kernel<<<(E + 255) / 256, 256, 0, stream>>>(srcv, dstv, cur, csr, E);
    // 3) h2 = relu(agg + b_gcn)
    agg_kernel<<<N_NODES / 4, 256, 0, stream>>>(xw, csr, degi, dinv, b_gcn, h2);
    // 4) hq = relu(h2 @ W1 + b1)
    mm_kernel<256, true, true><<<N_NODES / 16, 256, 0, stream>>>(h2, W1, b1, hq);
    // 5) q = hq @ W2 + b2
    qout_kernel<<<N_NODES / 4, 256, 0, stream>>>(hq, W2, b2, q);
}

// Round 2
// 897.324 us; speedup vs baseline: 1.4172x; 1.4172x over previous
//
#include <hip/hip_runtime.h>

#define N_NODES 100000
constexpr int F = 128;
constexpr int CAP = 128;  // padded-CSR capacity; in-deg ~ Poisson(32), P(>128) ~ e^-81

typedef __attribute__((ext_vector_type(8))) short short8;   // 8 bf16 (4 VGPRs)
typedef __attribute__((ext_vector_type(4))) float f32x4;    // MFMA C/D
typedef __attribute__((ext_vector_type(4))) short short4v;

__device__ inline short f2bf(float v) {
    union { float f; unsigned u; } x; x.f = v;
    unsigned r = (x.u + 0x7fff + ((x.u >> 16) & 1)) >> 16;  // round-nearest-even
    return (short)r;
}
__device__ inline float bf2f(unsigned us) {
    union { unsigned u; float f; } x; x.u = us << 16;
    return x.f;
}

// ---------- fp32 -> bf16 bulk convert (x) ----------
__global__ __launch_bounds__(256) void cvt_kernel(const float* __restrict__ in,
                                                  short* __restrict__ out, int n4) {
    int i = blockIdx.x * 256 + threadIdx.x;
    if (i < n4) {
        float4 v = reinterpret_cast<const float4*>(in)[i];
        short4v s; s.x = f2bf(v.x); s.y = f2bf(v.y); s.z = f2bf(v.z); s.w = f2bf(v.w);
        reinterpret_cast<short4v*>(out)[i] = s;
    }
}

// ---------- weight prep: W[K=128][H] -> Wt[H][128] bf16 ----------
__global__ __launch_bounds__(256) void wprep_kernel(const float* __restrict__ W,
                                                    short* __restrict__ Wt, int H) {
    int idx = blockIdx.x * 256 + threadIdx.x;  // idx over H*128
    if (idx < H * 128) {
        int h = idx >> 7, k = idx & 127;
        Wt[idx] = f2bf(W[(size_t)k * H + h]);
    }
}

// ---------- graph prep: fused degree+fill, then dinv ----------
__global__ __launch_bounds__(256) void fill_kernel(const int* __restrict__ src,
                                                   const int* __restrict__ dst,
                                                   int* __restrict__ cursor,
                                                   int* __restrict__ csr, int E) {
    int e = blockIdx.x * 256 + threadIdx.x;
    if (e < E) {
        int d = dst[e];
        int p = atomicAdd(&cursor[d], 1);
        if (p < CAP) csr[(size_t)d * CAP + p] = src[e];
    }
}

__global__ __launch_bounds__(256) void dinv_kernel(const int* __restrict__ degi,
                                                   float* __restrict__ dinv, int n) {
    int i = blockIdx.x * 256 + threadIdx.x;
    if (i < n) dinv[i] = rsqrtf(1.0f + (float)degi[i]);
}

// ---------- MFMA bf16 GEMM: out[n,H] = act(A[n,128] @ W[128,H] + b), bf16 out ----
// Wt is [H][128] (pre-transposed). Block = 4 waves x 16 rows = 64 rows.
// A-frag: A[m=lane&15][k=quad*8+j]; B-frag: Wt[n=lane&15 of tile][k=quad*8+j].
// C/D: col=lane&15, row=quad*4+reg (m89-verified layout).
template<int H, bool RELU, bool BIAS>
__global__ __launch_bounds__(256) void gemm_kernel(const short* __restrict__ Ab,
                                                   const short* __restrict__ Wt,
                                                   const float* __restrict__ bias,
                                                   short* __restrict__ out) {
    constexpr int NT = H / 16;
    const int wave = threadIdx.x >> 6;
    const int lane = threadIdx.x & 63;
    const int quad = lane >> 4;
    const int l16  = lane & 15;
    const int row0 = blockIdx.x * 64 + wave * 16;

    int arow = row0 + l16;
    if (arow >= N_NODES) arow = N_NODES - 1;  // clamp (stores masked)

    f32x4 acc[NT] = {};
#pragma unroll
    for (int kc = 0; kc < 4; ++kc) {
        short8 a = *reinterpret_cast<const short8*>(Ab + (size_t)arow * 128 + kc * 32 + quad * 8);
#pragma unroll
        for (int t = 0; t < NT; ++t) {
            short8 b = *reinterpret_cast<const short8*>(Wt + (size_t)(t * 16 + l16) * 128 + kc * 32 + quad * 8);
            acc[t] = __builtin_amdgcn_mfma_f32_16x16x32_bf16(a, b, acc[t], 0, 0, 0);
        }
    }
#pragma unroll
    for (int t = 0; t < NT; ++t) {
        float bv = 0.f;
        if (BIAS) bv = bias[t * 16 + l16];
#pragma unroll
        for (int r = 0; r < 4; ++r) {
            int row = row0 + quad * 4 + r;
            if (row < N_NODES) {
                float v = acc[t][r] + bv;
                if (RELU) v = fmaxf(v, 0.f);
                out[(size_t)row * H + t * 16 + l16] = f2bf(v);
            }
        }
    }
}

// ---------- aggregation (bf16 rows): h2 = relu(sum xw[src]*coef + xw*dinv^2 + b) ----
// one wave per node; 64 lanes x packed-bf16x2 = 128 features
__global__ __launch_bounds__(256) void agg_kernel(const short* __restrict__ xw,
                                                  const int* __restrict__ csr,
                                                  const int* __restrict__ degi,
                                                  const float* __restrict__ dinv,
                                                  const float* __restrict__ bg,
                                                  short* __restrict__ h2) {
    const int wave = threadIdx.x >> 6;
    const int lane = threadIdx.x & 63;
    const int node = blockIdx.x * 4 + wave;
    if (node >= N_NODES) return;

    int d = degi[node];
    if (d > CAP) d = CAP;
    const float dv = dinv[node];
    const int* row = csr + (size_t)node * CAP;

    float ax = 0.f, ay = 0.f;
#pragma unroll 2
    for (int j = 0; j < d; ++j) {
        int s = __builtin_amdgcn_readfirstlane(row[j]);
        float c = dinv[s] * dv;
        unsigned v = *reinterpret_cast<const unsigned*>(xw + (size_t)s * F + lane * 2);
        ax = fmaf(bf2f(v & 0xffffu), c, ax);
        ay = fmaf(bf2f(v >> 16), c, ay);
    }
    const float sc = dv * dv;
    unsigned vs = *reinterpret_cast<const unsigned*>(xw + (size_t)node * F + lane * 2);
    ax = fmaf(bf2f(vs & 0xffffu), sc, ax);
    ay = fmaf(bf2f(vs >> 16), sc, ay);
    ax = fmaxf(ax + bg[lane * 2 + 0], 0.f);
    ay = fmaxf(ay + bg[lane * 2 + 1], 0.f);
    unsigned o = (unsigned)(unsigned short)f2bf(ax) | ((unsigned)(unsigned short)f2bf(ay) << 16);
    *reinterpret_cast<unsigned*>(h2 + (size_t)node * F + lane * 2) = o;
}

// ---------- final layer: q[n,10] = hq[n,256](bf16) @ W2[256,10] + b2 ----------
__global__ __launch_bounds__(256) void qout_kernel(const short* __restrict__ hq,
                                                   const float* __restrict__ W2,
                                                   const float* __restrict__ b2,
                                                   float* __restrict__ q) {
    const int wave = threadIdx.x >> 6;
    const int lane = threadIdx.x & 63;
    const int node = blockIdx.x * 4 + wave;
    if (node >= N_NODES) return;

    short4v hs = reinterpret_cast<const short4v*>(hq + (size_t)node * 256)[lane];
    float h0 = bf2f((unsigned short)hs.x), h1 = bf2f((unsigned short)hs.y);
    float h2 = bf2f((unsigned short)hs.z), h3 = bf2f((unsigned short)hs.w);
    const float* w = W2 + (size_t)lane * 4 * 10;

    float acc[10];
#pragma unroll
    for (int o = 0; o < 10; ++o)
        acc[o] = h0 * w[o] + h1 * w[10 + o] + h2 * w[20 + o] + h3 * w[30 + o];
#pragma unroll
    for (int o = 0; o < 10; ++o) {
#pragma unroll
        for (int off = 32; off > 0; off >>= 1)
            acc[o] += __shfl_xor(acc[o], off, 64);
    }
    if (lane < 10) {
        float v = 0.f;
#pragma unroll
        for (int o = 0; o < 10; ++o)
            if (lane == o) v = acc[o];
        q[(size_t)node * 10 + lane] = v + b2[lane];
    }
}

extern "C" void kernel_launch(void* const* d_in, const int* in_sizes, int n_in,
                              void* d_out, int out_size, void* d_ws, size_t ws_size,
                              hipStream_t stream) {
    const float* x     = (const float*)d_in[0];
    const int*   ei    = (const int*)d_in[1];
    const float* W_enc = (const float*)d_in[2];
    const float* b_enc = (const float*)d_in[3];
    const float* W_gcn = (const float*)d_in[4];
    const float* b_gcn = (const float*)d_in[5];
    const float* W1    = (const float*)d_in[6];
    const float* b1    = (const float*)d_in[7];
    const float* W2    = (const float*)d_in[8];
    const float* b2    = (const float*)d_in[9];
    float* q = (float*)d_out;

    const int E = in_sizes[1] / 2;
    const int* srcv = ei;
    const int* dstv = ei + E;

    // workspace layout (bytes). bf16 activations: N*F*2 = 25.6 MB each.
    char* ws = (char*)d_ws;
    const size_t NFB = (size_t)N_NODES * F * sizeof(short);       // 25,600,000
    short* xb  = (short*)(ws);                    // [0, 25.6M)   x bf16; freed after gemm1
    short* h2a = (short*)(ws);                    //   overlay: agg output
    short* h   = (short*)(ws + NFB);              // [25.6M, 51.2M)
    short* xw  = (short*)(ws + 2 * NFB);          // [51.2M, 76.8M)
    short* hq  = (short*)(ws + NFB);              //   overlay h+xw: 51.2 MB (after agg)
    int*   csr = (int*)  (ws + 3 * NFB);          // [76.8M, 128M)  CAP*4*N = 51.2 MB
    char*  tail = ws + 3 * NFB + (size_t)N_NODES * CAP * sizeof(int);
    int*   cur  = (int*)(tail);                   // 400 KB (doubles as degree)
    float* dinv = (float*)(tail + 512 * 1024);
    short* Wte  = (short*)(tail + 1024 * 1024);               // 32 KB
    short* Wtg  = (short*)(tail + 1024 * 1024 + 64 * 1024);   // 32 KB
    short* Wt1  = (short*)(tail + 1024 * 1024 + 128 * 1024);  // 64 KB

    hipMemsetAsync(cur, 0, N_NODES * sizeof(int), stream);

    cvt_kernel<<<(N_NODES * F / 4 + 255) / 256, 256, 0, stream>>>(x, xb, N_NODES * F / 4);
    wprep_kernel<<<(128 * 128 + 255) / 256, 256, 0, stream>>>(W_enc, Wte, 128);
    wprep_kernel<<<(128 * 128 + 255) / 256, 256, 0, stream>>>(W_gcn, Wtg, 128);
    wprep_kernel<<<(256 * 128 + 255) / 256, 256, 0, stream>>>(W1, Wt1, 256);
    fill_kernel<<<(E + 255) / 256, 256, 0, stream>>>(srcv, dstv, cur, csr, E);
    dinv_kernel<<<(N_NODES + 255) / 256, 256, 0, stream>>>(cur, dinv, N_NODES);

    // 1) h = relu(x @ W_enc + b_enc)
    gemm_kernel<128, true, true><<<(N_NODES + 63) / 64, 256, 0, stream>>>(xb, Wte, b_enc, h);
    // 2) xw = h @ W_gcn
    gemm_kernel<128, false, false><<<(N_NODES + 63) / 64, 256, 0, stream>>>(h, Wtg, nullptr, xw);
    // 3) h2 = relu(agg + b_gcn)
    agg_kernel<<<N_NODES / 4, 256, 0, stream>>>(xw, csr, cur, dinv, b_gcn, h2a);
    // 4) hq = relu(h2 @ W1 + b1)
    gemm_kernel<256, true, true><<<(N_NODES + 63) / 64, 256, 0, stream>>>(h2a, Wt1, b1, hq);
    // 5) q = hq @ W2 + b2
    qout_kernel<<<N_NODES / 4, 256, 0, stream>>>(hq, W2, b2, q);
}

// Round 3
// 584.652 us; speedup vs baseline: 2.1751x; 1.5348x over previous
//
#include <hip/hip_runtime.h>

#define N_NODES 100000
constexpr int F = 128;
constexpr int CAP = 128;  // padded-CSR capacity; in-deg ~ Poisson(32), P(>128) ~ e^-81

typedef __attribute__((ext_vector_type(8))) short short8;   // 8 bf16 (4 VGPRs)
typedef __attribute__((ext_vector_type(4))) float f32x4;    // MFMA C/D
typedef __attribute__((ext_vector_type(4))) short short4v;

__device__ inline short f2bf(float v) {
    union { float f; unsigned u; } x; x.f = v;
    unsigned r = (x.u + 0x7fff + ((x.u >> 16) & 1)) >> 16;  // round-nearest-even
    return (short)r;
}
__device__ inline float bf2f(unsigned us) {
    union { unsigned u; float f; } x; x.u = us << 16;
    return x.f;
}

// ---------- combined weight prep: transpose->bf16 for all 4 weight mats ----------
// Wte[128][128], Wtg[128][128], Wt1[256][128], W2t[16][256] (cols 10..15 zero)
__global__ __launch_bounds__(256) void prep_kernel(const float* __restrict__ W_enc,
                                                   const float* __restrict__ W_gcn,
                                                   const float* __restrict__ W1,
                                                   const float* __restrict__ W2,
                                                   short* __restrict__ Wte,
                                                   short* __restrict__ Wtg,
                                                   short* __restrict__ Wt1,
                                                   short* __restrict__ W2t) {
    int idx = blockIdx.x * 256 + threadIdx.x;
    if (idx < 16384) { int h = idx >> 7, k = idx & 127; Wte[idx] = f2bf(W_enc[k * 128 + h]); return; }
    idx -= 16384;
    if (idx < 16384) { int h = idx >> 7, k = idx & 127; Wtg[idx] = f2bf(W_gcn[k * 128 + h]); return; }
    idx -= 16384;
    if (idx < 32768) { int h = idx >> 7, k = idx & 127; Wt1[idx] = f2bf(W1[k * 256 + h]); return; }
    idx -= 32768;
    if (idx < 4096)  { int n = idx >> 8, k = idx & 255; W2t[idx] = (n < 10) ? f2bf(W2[k * 10 + n]) : (short)0; }
}

// ---------- graph prep ----------
__global__ __launch_bounds__(256) void fill_kernel(const int* __restrict__ src,
                                                   const int* __restrict__ dst,
                                                   int* __restrict__ cursor,
                                                   int* __restrict__ csr, int E) {
    int e = blockIdx.x * 256 + threadIdx.x;
    if (e < E) {
        int d = dst[e];
        int p = atomicAdd(&cursor[d], 1);
        if (p < CAP) csr[(size_t)d * CAP + p] = src[e];
    }
}

__global__ __launch_bounds__(256) void dinv_kernel(const int* __restrict__ degi,
                                                   float* __restrict__ dinv, int n) {
    int i = blockIdx.x * 256 + threadIdx.x;
    if (i < n) dinv[i] = rsqrtf(1.0f + (float)degi[i]);
}

// ---------- MFMA bf16 GEMM: out[n,H] = act(A[n,128] @ W[128,H] + b), bf16 out ----
// a-operand = weight rows (m = output-feature), b-operand = node rows (n = node).
// D: col(lane&15)=node, row(quad*4+r)=feature -> 8B contiguous stores per tile.
template<int H, bool RELU, bool BIAS, bool AFP32>
__global__ __launch_bounds__(256) void gemm_kernel(const void* __restrict__ Ain,
                                                   const short* __restrict__ Wt,
                                                   const float* __restrict__ bias,
                                                   short* __restrict__ out) {
    constexpr int NT = H / 16;
    const int wave = threadIdx.x >> 6;
    const int lane = threadIdx.x & 63;
    const int quad = lane >> 4;
    const int l16  = lane & 15;
    const int node0 = blockIdx.x * 64 + wave * 16;

    int nrow = node0 + l16;
    const bool valid = nrow < N_NODES;
    if (!valid) nrow = N_NODES - 1;

    f32x4 acc[NT] = {};
#pragma unroll
    for (int kc = 0; kc < 4; ++kc) {
        short8 xfrag;
        if (AFP32) {
            const float* ap = (const float*)Ain + (size_t)nrow * 128 + kc * 32 + quad * 8;
            float4 f0 = *reinterpret_cast<const float4*>(ap);
            float4 f1 = *reinterpret_cast<const float4*>(ap + 4);
            xfrag.s0 = f2bf(f0.x); xfrag.s1 = f2bf(f0.y); xfrag.s2 = f2bf(f0.z); xfrag.s3 = f2bf(f0.w);
            xfrag.s4 = f2bf(f1.x); xfrag.s5 = f2bf(f1.y); xfrag.s6 = f2bf(f1.z); xfrag.s7 = f2bf(f1.w);
        } else {
            xfrag = *reinterpret_cast<const short8*>((const short*)Ain + (size_t)nrow * 128 + kc * 32 + quad * 8);
        }
#pragma unroll
        for (int t = 0; t < NT; ++t) {
            short8 wfrag = *reinterpret_cast<const short8*>(Wt + (size_t)(t * 16 + l16) * 128 + kc * 32 + quad * 8);
            acc[t] = __builtin_amdgcn_mfma_f32_16x16x32_bf16(wfrag, xfrag, acc[t], 0, 0, 0);
        }
    }
    if (!valid) return;
#pragma unroll
    for (int t = 0; t < NT; ++t) {
        short4v o;
#pragma unroll
        for (int r = 0; r < 4; ++r) {
            float v = acc[t][r];
            if (BIAS) v += bias[t * 16 + quad * 4 + r];
            if (RELU) v = fmaxf(v, 0.f);
            ((short*)&o)[r] = f2bf(v);
        }
        *reinterpret_cast<short4v*>(out + (size_t)nrow * H + t * 16 + quad * 4) = o;
    }
}

// ---------- aggregation: h2 = relu(sum xw[src]*coef + xw*dinv^2 + b) ----------
// one wave per node; edge list prefetched lane-parallel into registers,
// broadcast per edge via __shfl -> inner loop has ONE memory op per edge, x8 unrolled.
__global__ __launch_bounds__(256) void agg_kernel(const short* __restrict__ xw,
                                                  const int* __restrict__ csr,
                                                  const int* __restrict__ degi,
                                                  const float* __restrict__ dinv,
                                                  const float* __restrict__ bg,
                                                  short* __restrict__ h2) {
    const int wave = threadIdx.x >> 6;
    const int lane = threadIdx.x & 63;
    const int node = blockIdx.x * 4 + wave;
    if (node >= N_NODES) return;

    int d = degi[node];
    if (d > CAP) d = CAP;
    const float dv = dinv[node];
    const int* row = csr + (size_t)node * CAP;

    // lane-parallel entry prefetch; pad with (self, 0) so inner loop is branch-free
    int s0 = node, s1 = node;
    float c0 = 0.f, c1 = 0.f;
    if (lane < d)      { s0 = row[lane];      c0 = dinv[s0] * dv; }
    if (lane + 64 < d) { s1 = row[lane + 64]; c1 = dinv[s1] * dv; }

    float ax = 0.f, ay = 0.f;
    const int dpad = (d + 7) & ~7;
    const int n0 = dpad < 64 ? dpad : 64;
    for (int j0 = 0; j0 < n0; j0 += 8) {
#pragma unroll
        for (int u = 0; u < 8; ++u) {
            int   sj = __shfl(s0, j0 + u, 64);
            float cj = __shfl(c0, j0 + u, 64);
            unsigned v = *(reinterpret_cast<const unsigned*>(xw + ((size_t)sj << 7)) + lane);
            ax = fmaf(bf2f(v & 0xffffu), cj, ax);
            ay = fmaf(bf2f(v >> 16), cj, ay);
        }
    }
    for (int j0 = 64; j0 < dpad; j0 += 8) {
#pragma unroll
        for (int u = 0; u < 8; ++u) {
            int   sj = __shfl(s1, j0 + u - 64, 64);
            float cj = __shfl(c1, j0 + u - 64, 64);
            unsigned v = *(reinterpret_cast<const unsigned*>(xw + ((size_t)sj << 7)) + lane);
            ax = fmaf(bf2f(v & 0xffffu), cj, ax);
            ay = fmaf(bf2f(v >> 16), cj, ay);
        }
    }
    // self-loop
    const float sc = dv * dv;
    unsigned vs = *(reinterpret_cast<const unsigned*>(xw + ((size_t)node << 7)) + lane);
    ax = fmaf(bf2f(vs & 0xffffu), sc, ax);
    ay = fmaf(bf2f(vs >> 16), sc, ay);
    // bias + relu
    ax = fmaxf(ax + bg[lane * 2 + 0], 0.f);
    ay = fmaxf(ay + bg[lane * 2 + 1], 0.f);
    unsigned o = (unsigned)(unsigned short)f2bf(ax) | ((unsigned)(unsigned short)f2bf(ay) << 16);
    *(reinterpret_cast<unsigned*>(h2 + ((size_t)node << 7)) + lane) = o;
}

// ---------- final layer via MFMA: q[n,10] = hq[n,256] @ W2[256,10] + b2 ----------
// a-operand = hq rows (m=node), b-operand = W2t padded to 16 cols (n=outdim).
// D: col(l16)=outdim, row(quad*4+r)=node offset.
__global__ __launch_bounds__(256) void qout_kernel(const short* __restrict__ hq,
                                                   const short* __restrict__ W2t,
                                                   const float* __restrict__ b2,
                                                   float* __restrict__ q) {
    const int wave = threadIdx.x >> 6;
    const int lane = threadIdx.x & 63;
    const int quad = lane >> 4;
    const int l16  = lane & 15;
    const int node0 = blockIdx.x * 64 + wave * 16;

    int nrow = node0 + l16;
    if (nrow >= N_NODES) nrow = N_NODES - 1;

    f32x4 acc = {};
#pragma unroll
    for (int kc = 0; kc < 8; ++kc) {
        short8 a = *reinterpret_cast<const short8*>(hq + (size_t)nrow * 256 + kc * 32 + quad * 8);
        short8 b = *reinterpret_cast<const short8*>(W2t + (size_t)l16 * 256 + kc * 32 + quad * 8);
        acc = __builtin_amdgcn_mfma_f32_16x16x32_bf16(a, b, acc, 0, 0, 0);
    }
    if (l16 < 10) {
        float bv = b2[l16];
#pragma unroll
        for (int r = 0; r < 4; ++r) {
            int nd = node0 + quad * 4 + r;
            if (nd < N_NODES) q[(size_t)nd * 10 + l16] = acc[r] + bv;
        }
    }
}

extern "C" void kernel_launch(void* const* d_in, const int* in_sizes, int n_in,
                              void* d_out, int out_size, void* d_ws, size_t ws_size,
                              hipStream_t stream) {
    const float* x     = (const float*)d_in[0];
    const int*   ei    = (const int*)d_in[1];
    const float* W_enc = (const float*)d_in[2];
    const float* b_enc = (const float*)d_in[3];
    const float* W_gcn = (const float*)d_in[4];
    const float* b_gcn = (const float*)d_in[5];
    const float* W1    = (const float*)d_in[6];
    const float* b1    = (const float*)d_in[7];
    const float* W2    = (const float*)d_in[8];
    const float* b2    = (const float*)d_in[9];
    float* q = (float*)d_out;

    const int E = in_sizes[1] / 2;
    const int* srcv = ei;
    const int* dstv = ei + E;

    // workspace layout (bytes): h/h2 25.6M | xw 25.6M | hq 51.2M | csr 51.2M | tail
    char* ws = (char*)d_ws;
    const size_t NFB = (size_t)N_NODES * F * sizeof(short);  // 25,600,000
    short* h   = (short*)(ws);                // gemm1 out; overlaid by h2 (agg out) after gemm2
    short* h2a = (short*)(ws);
    short* xw  = (short*)(ws + NFB);
    short* hq  = (short*)(ws + 2 * NFB);      // 51.2 MB
    int*   csr = (int*)  (ws + 4 * NFB);      // 51.2 MB
    char*  tail = ws + 6 * NFB;
    int*   cur  = (int*)(tail);               // 400 KB (doubles as in-degree)
    float* dinv = (float*)(tail + 400000);
    short* Wte  = (short*)(tail + 800000);
    short* Wtg  = (short*)(tail + 832768);
    short* Wt1  = (short*)(tail + 865536);
    short* W2t  = (short*)(tail + 931072);
    // end ~= 6*NFB + 940K ~= 154.5 MB

    hipMemsetAsync(cur, 0, N_NODES * sizeof(int), stream);
    prep_kernel<<<272, 256, 0, stream>>>(W_enc, W_gcn, W1, W2, Wte, Wtg, Wt1, W2t);
    fill_kernel<<<(E + 255) / 256, 256, 0, stream>>>(srcv, dstv, cur, csr, E);
    dinv_kernel<<<(N_NODES + 255) / 256, 256, 0, stream>>>(cur, dinv, N_NODES);

    // 1) h = relu(x @ W_enc + b_enc)   (fp32 A converted in-register)
    gemm_kernel<128, true, true, true><<<(N_NODES + 63) / 64, 256, 0, stream>>>(x, Wte, b_enc, h);
    // 2) xw = h @ W_gcn
    gemm_kernel<128, false, false, false><<<(N_NODES + 63) / 64, 256, 0, stream>>>(h, Wtg, nullptr, xw);
    // 3) h2 = relu(agg(xw) + b_gcn)
    agg_kernel<<<N_NODES / 4, 256, 0, stream>>>(xw, csr, cur, dinv, b_gcn, h2a);
    // 4) hq = relu(h2 @ W1 + b1)
    gemm_kernel<256, true, true, false><<<(N_NODES + 63) / 64, 256, 0, stream>>>(h2a, Wt1, b1, hq);
    // 5) q = hq @ W2 + b2
    qout_kernel<<<(N_NODES + 63) / 64, 256, 0, stream>>>(hq, W2t, b2, q);
}

// Round 4
// 472.417 us; speedup vs baseline: 2.6919x; 1.2376x over previous
//
#include <hip/hip_runtime.h>

#define N_NODES 100000
constexpr int F    = 128;
constexpr int NB   = (N_NODES + 63) / 64;  // 1563 buckets of 64 dst-nodes
constexpr int BCAP = 2560;                 // bucket capacity (mean 2048, +11 sigma)
constexpr int LCAP = 80;                   // per-node LDS CSR cap (max in-deg ~65 for Poisson(32))
constexpr int CHUNK = 8192;                // edges per partition block

typedef __attribute__((ext_vector_type(8))) short short8;   // 8 bf16 (4 VGPRs)
typedef __attribute__((ext_vector_type(4))) float f32x4;    // MFMA C/D
typedef __attribute__((ext_vector_type(4))) short short4v;

__device__ inline short f2bf(float v) {
    union { float f; unsigned u; } x; x.f = v;
    unsigned r = (x.u + 0x7fff + ((x.u >> 16) & 1)) >> 16;  // round-nearest-even
    return (short)r;
}
__device__ inline float bf2f(unsigned us) {
    union { unsigned u; float f; } x; x.u = us << 16;
    return x.f;
}

// ---------- combined weight prep: transpose->bf16 for all 4 weight mats ----------
__global__ __launch_bounds__(256) void prep_kernel(const float* __restrict__ W_enc,
                                                   const float* __restrict__ W_gcn,
                                                   const float* __restrict__ W1,
                                                   const float* __restrict__ W2,
                                                   short* __restrict__ Wte,
                                                   short* __restrict__ Wtg,
                                                   short* __restrict__ Wt1,
                                                   short* __restrict__ W2t) {
    int idx = blockIdx.x * 256 + threadIdx.x;
    if (idx < 16384) { int h = idx >> 7, k = idx & 127; Wte[idx] = f2bf(W_enc[k * 128 + h]); return; }
    idx -= 16384;
    if (idx < 16384) { int h = idx >> 7, k = idx & 127; Wtg[idx] = f2bf(W_gcn[k * 128 + h]); return; }
    idx -= 16384;
    if (idx < 32768) { int h = idx >> 7, k = idx & 127; Wt1[idx] = f2bf(W1[k * 256 + h]); return; }
    idx -= 32768;
    if (idx < 4096)  { int n = idx >> 8, k = idx & 255; W2t[idx] = (n < 10) ? f2bf(W2[k * 10 + n]) : (short)0; }
}

// ---------- partition edges into 64-node dst-buckets (packed src | local_dst<<17) ----
__global__ __launch_bounds__(256) void part_kernel(const int* __restrict__ src,
                                                   const int* __restrict__ dst,
                                                   int* __restrict__ bcur,
                                                   int* __restrict__ part, int E) {
    __shared__ int cnt[NB];
    __shared__ int base[NB];
    for (int b = threadIdx.x; b < NB; b += 256) cnt[b] = 0;
    __syncthreads();
    const int e0 = blockIdx.x * CHUNK;
    const int e1 = min(e0 + CHUNK, E);
    for (int e = e0 + threadIdx.x; e < e1; e += 256)
        atomicAdd(&cnt[dst[e] >> 6], 1);
    __syncthreads();
    for (int b = threadIdx.x; b < NB; b += 256) {
        int c = cnt[b];
        base[b] = c ? atomicAdd(&bcur[b], c) : 0;
        cnt[b] = 0;  // reuse as local cursor
    }
    __syncthreads();
    for (int e = e0 + threadIdx.x; e < e1; e += 256) {
        int d = dst[e];
        int b = d >> 6;
        int idx = base[b] + atomicAdd(&cnt[b], 1);
        if (idx < BCAP) part[b * BCAP + idx] = src[e] | ((d & 63) << 17);
    }
}

// ---------- per-node in-degree from partitioned edges (coalesced store) ----------
__global__ __launch_bounds__(256) void bdeg_kernel(const int* __restrict__ bcur,
                                                   const int* __restrict__ part,
                                                   int* __restrict__ degi) {
    __shared__ int cur[64];
    const int b = blockIdx.x;
    if (threadIdx.x < 64) cur[threadIdx.x] = 0;
    __syncthreads();
    const int cnt = min(bcur[b], BCAP);
    const int* p = part + (size_t)b * BCAP;
    for (int i = threadIdx.x; i < cnt; i += 256)
        atomicAdd(&cur[(p[i] >> 17) & 63], 1);
    __syncthreads();
    const int node = b * 64 + threadIdx.x;
    if (threadIdx.x < 64 && node < N_NODES) degi[node] = cur[threadIdx.x];
}

// ---------- MFMA bf16 GEMM: out[n,H] = act(A[n,128] @ W[128,H] + b), bf16 out ----
template<int H, bool RELU, bool BIAS, bool AFP32>
__global__ __launch_bounds__(256) void gemm_kernel(const void* __restrict__ Ain,
                                                   const short* __restrict__ Wt,
                                                   const float* __restrict__ bias,
                                                   short* __restrict__ out) {
    constexpr int NT = H / 16;
    const int wave = threadIdx.x >> 6;
    const int lane = threadIdx.x & 63;
    const int quad = lane >> 4;
    const int l16  = lane & 15;
    const int node0 = blockIdx.x * 64 + wave * 16;

    int nrow = node0 + l16;
    const bool valid = nrow < N_NODES;
    if (!valid) nrow = N_NODES - 1;

    f32x4 acc[NT] = {};
#pragma unroll
    for (int kc = 0; kc < 4; ++kc) {
        short8 xfrag;
        if (AFP32) {
            const float* ap = (const float*)Ain + (size_t)nrow * 128 + kc * 32 + quad * 8;
            float4 f0 = *reinterpret_cast<const float4*>(ap);
            float4 f1 = *reinterpret_cast<const float4*>(ap + 4);
            xfrag.s0 = f2bf(f0.x); xfrag.s1 = f2bf(f0.y); xfrag.s2 = f2bf(f0.z); xfrag.s3 = f2bf(f0.w);
            xfrag.s4 = f2bf(f1.x); xfrag.s5 = f2bf(f1.y); xfrag.s6 = f2bf(f1.z); xfrag.s7 = f2bf(f1.w);
        } else {
            xfrag = *reinterpret_cast<const short8*>((const short*)Ain + (size_t)nrow * 128 + kc * 32 + quad * 8);
        }
#pragma unroll
        for (int t = 0; t < NT; ++t) {
            short8 wfrag = *reinterpret_cast<const short8*>(Wt + (size_t)(t * 16 + l16) * 128 + kc * 32 + quad * 8);
            acc[t] = __builtin_amdgcn_mfma_f32_16x16x32_bf16(wfrag, xfrag, acc[t], 0, 0, 0);
        }
    }
    if (!valid) return;
#pragma unroll
    for (int t = 0; t < NT; ++t) {
        short4v o;
#pragma unroll
        for (int r = 0; r < 4; ++r) {
            float v = acc[t][r];
            if (BIAS) v += bias[t * 16 + quad * 4 + r];
            if (RELU) v = fmaxf(v, 0.f);
            ((short*)&o)[r] = f2bf(v);
        }
        *reinterpret_cast<short4v*>(out + (size_t)nrow * H + t * 16 + quad * 4) = o;
    }
}

// ---------- fused LDS-CSR build + aggregation per 64-node bucket ----------
// h2 = relu(sum xw[src]*coef + xw*dinv^2 + b_gcn)
__global__ __launch_bounds__(256) void agg_kernel(const short* __restrict__ xw,
                                                  const int* __restrict__ bcur,
                                                  const int* __restrict__ part,
                                                  const int* __restrict__ degi,
                                                  const float* __restrict__ bg,
                                                  short* __restrict__ h2) {
    __shared__ int csr_l[64 * LCAP];   // 20480 B
    __shared__ int cur[64];
    const int b = blockIdx.x;
    if (threadIdx.x < 64) cur[threadIdx.x] = 0;
    __syncthreads();
    const int cnt = min(bcur[b], BCAP);
    const int* p = part + (size_t)b * BCAP;
    for (int i = threadIdx.x; i < cnt; i += 256) {
        int v = p[i];
        int ld = (v >> 17) & 63;
        int pos = atomicAdd(&cur[ld], 1);
        if (pos < LCAP) csr_l[ld * LCAP + pos] = v & 0x1FFFF;
    }
    __syncthreads();

    const int wave = threadIdx.x >> 6;
    const int lane = threadIdx.x & 63;
    for (int t = 0; t < 16; ++t) {
        const int ld = wave * 16 + t;
        const int node = b * 64 + ld;
        if (node >= N_NODES) break;  // uniform across wave

        const int dtrue = cur[ld];
        const int d = min(dtrue, LCAP);
        const float dv = rsqrtf(1.f + (float)dtrue);

        // lane-parallel prefetch of (src, coef); pad with (self, 0)
        int s0 = node, s1 = node;
        float c0 = 0.f, c1 = 0.f;
        if (lane < d)      { s0 = csr_l[ld * LCAP + lane];      c0 = rsqrtf(1.f + (float)degi[s0]) * dv; }
        if (lane + 64 < d) { s1 = csr_l[ld * LCAP + lane + 64]; c1 = rsqrtf(1.f + (float)degi[s1]) * dv; }

        float ax = 0.f, ay = 0.f;
        const int dpad = (d + 7) & ~7;
        const int n0 = dpad < 64 ? dpad : 64;
        for (int j0 = 0; j0 < n0; j0 += 8) {
#pragma unroll
            for (int u = 0; u < 8; ++u) {
                int   sj = __shfl(s0, j0 + u, 64);
                float cj = __shfl(c0, j0 + u, 64);
                unsigned v = *(reinterpret_cast<const unsigned*>(xw + ((size_t)sj << 7)) + lane);
                ax = fmaf(bf2f(v & 0xffffu), cj, ax);
                ay = fmaf(bf2f(v >> 16), cj, ay);
            }
        }
        for (int j0 = 64; j0 < dpad; j0 += 8) {
#pragma unroll
            for (int u = 0; u < 8; ++u) {
                int   sj = __shfl(s1, j0 + u - 64, 64);
                float cj = __shfl(c1, j0 + u - 64, 64);
                unsigned v = *(reinterpret_cast<const unsigned*>(xw + ((size_t)sj << 7)) + lane);
                ax = fmaf(bf2f(v & 0xffffu), cj, ax);
                ay = fmaf(bf2f(v >> 16), cj, ay);
            }
        }
        // self-loop + bias + relu
        const float sc = dv * dv;
        unsigned vs = *(reinterpret_cast<const unsigned*>(xw + ((size_t)node << 7)) + lane);
        ax = fmaf(bf2f(vs & 0xffffu), sc, ax);
        ay = fmaf(bf2f(vs >> 16), sc, ay);
        ax = fmaxf(ax + bg[lane * 2 + 0], 0.f);
        ay = fmaxf(ay + bg[lane * 2 + 1], 0.f);
        unsigned o = (unsigned)(unsigned short)f2bf(ax) | ((unsigned)(unsigned short)f2bf(ay) << 16);
        *(reinterpret_cast<unsigned*>(h2 + ((size_t)node << 7)) + lane) = o;
    }
}

// ---------- final layer via MFMA: q[n,10] = hq[n,256] @ W2[256,10] + b2 ----------
__global__ __launch_bounds__(256) void qout_kernel(const short* __restrict__ hq,
                                                   const short* __restrict__ W2t,
                                                   const float* __restrict__ b2,
                                                   float* __restrict__ q) {
    const int wave = threadIdx.x >> 6;
    const int lane = threadIdx.x & 63;
    const int quad = lane >> 4;
    const int l16  = lane & 15;
    const int node0 = blockIdx.x * 64 + wave * 16;

    int nrow = node0 + l16;
    if (nrow >= N_NODES) nrow = N_NODES - 1;

    f32x4 acc = {};
#pragma unroll
    for (int kc = 0; kc < 8; ++kc) {
        short8 a = *reinterpret_cast<const short8*>(hq + (size_t)nrow * 256 + kc * 32 + quad * 8);
        short8 b = *reinterpret_cast<const short8*>(W2t + (size_t)l16 * 256 + kc * 32 + quad * 8);
        acc = __builtin_amdgcn_mfma_f32_16x16x32_bf16(a, b, acc, 0, 0, 0);
    }
    if (l16 < 10) {
        float bv = b2[l16];
#pragma unroll
        for (int r = 0; r < 4; ++r) {
            int nd = node0 + quad * 4 + r;
            if (nd < N_NODES) q[(size_t)nd * 10 + l16] = acc[r] + bv;
        }
    }
}

extern "C" void kernel_launch(void* const* d_in, const int* in_sizes, int n_in,
                              void* d_out, int out_size, void* d_ws, size_t ws_size,
                              hipStream_t stream) {
    const float* x     = (const float*)d_in[0];
    const int*   ei    = (const int*)d_in[1];
    const float* W_enc = (const float*)d_in[2];
    const float* b_enc = (const float*)d_in[3];
    const float* W_gcn = (const float*)d_in[4];
    const float* b_gcn = (const float*)d_in[5];
    const float* W1    = (const float*)d_in[6];
    const float* b1    = (const float*)d_in[7];
    const float* W2    = (const float*)d_in[8];
    const float* b2    = (const float*)d_in[9];
    float* q = (float*)d_out;

    const int E = in_sizes[1] / 2;
    const int* srcv = ei;
    const int* dstv = ei + E;

    // workspace: h/h2 25.6M | xw 25.6M | hq 51.2M | part 16M | tail
    char* ws = (char*)d_ws;
    const size_t NFB = (size_t)N_NODES * F * sizeof(short);  // 25,600,000
    short* h    = (short*)(ws);               // gemm1 out; overlaid by h2 (agg out)
    short* h2a  = (short*)(ws);
    short* xw   = (short*)(ws + NFB);
    short* hq   = (short*)(ws + 2 * NFB);     // 51.2 MB
    int*   part = (int*)  (ws + 4 * NFB);     // NB*BCAP*4 = 16,005,120 B
    char*  tail = ws + 4 * NFB + (size_t)NB * BCAP * sizeof(int);
    int*   bcr  = (int*)(tail);               // NB*4 = 6252 B
    int*   degi = (int*)(tail + 8192);        // 400 KB
    short* Wte  = (short*)(tail + 8192 + 400000);
    short* Wtg  = (short*)(tail + 8192 + 400000 + 32768);
    short* Wt1  = (short*)(tail + 8192 + 400000 + 65536);
    short* W2t  = (short*)(tail + 8192 + 400000 + 131072);
    // end ~= 4*NFB + 16.6 MB ~= 119 MB

    hipMemsetAsync(bcr, 0, NB * sizeof(int), stream);
    prep_kernel<<<272, 256, 0, stream>>>(W_enc, W_gcn, W1, W2, Wte, Wtg, Wt1, W2t);
    part_kernel<<<(E + CHUNK - 1) / CHUNK, 256, 0, stream>>>(srcv, dstv, bcr, part, E);
    bdeg_kernel<<<NB, 256, 0, stream>>>(bcr, part, degi);

    // 1) h = relu(x @ W_enc + b_enc)   (fp32 A converted in-register)
    gemm_kernel<128, true, true, true><<<NB, 256, 0, stream>>>(x, Wte, b_enc, h);
    // 2) xw = h @ W_gcn
    gemm_kernel<128, false, false, false><<<NB, 256, 0, stream>>>(h, Wtg, nullptr, xw);
    // 3) h2 = relu(agg(xw) + b_gcn)  (fused LDS-CSR + gather)
    agg_kernel<<<NB, 256, 0, stream>>>(xw, bcr, part, degi, b_gcn, h2a);
    // 4) hq = relu(h2 @ W1 + b1)
    gemm_kernel<256, true, true, false><<<NB, 256, 0, stream>>>(h2a, Wt1, b1, hq);
    // 5) q = hq @ W2 + b2
    qout_kernel<<<NB, 256, 0, stream>>>(hq, W2t, b2, q);
}

// Round 5
// 463.699 us; speedup vs baseline: 2.7425x; 1.0188x over previous
//
#include <hip/hip_runtime.h>

#define N_NODES 100000
constexpr int F     = 128;
constexpr int NB    = (N_NODES + 63) / 64;  // 1563 buckets of 64 dst-nodes
constexpr int BCAP  = 2560;                 // bucket capacity (mean 2048, +11 sigma)
constexpr int LCAP  = 80;                   // per-node LDS CSR cap (max in-deg ~65)
constexpr int CHUNK = 32768;                // edges per partition block
constexpr int PADN  = N_NODES;              // zero-row index for edge-list padding

typedef __attribute__((ext_vector_type(8))) short short8;   // 8 bf16 (4 VGPRs)
typedef __attribute__((ext_vector_type(4))) float f32x4;    // MFMA C/D
typedef __attribute__((ext_vector_type(4))) short short4v;

__device__ inline short f2bf(float v) {
    union { float f; unsigned u; } x; x.f = v;
    unsigned r = (x.u + 0x7fff + ((x.u >> 16) & 1)) >> 16;  // round-nearest-even
    return (short)r;
}
__device__ inline float lo_bf(unsigned v) {  // low bf16 -> f32 (1 VALU op)
    union { unsigned u; float f; } x; x.u = v << 16; return x.f;
}
__device__ inline float hi_bf(unsigned v) {  // high bf16 -> f32 (1 VALU op)
    union { unsigned u; float f; } x; x.u = v & 0xffff0000u; return x.f;
}

// ---------- weight prep (transpose->bf16) + bcr zeroing ----------
__global__ __launch_bounds__(256) void prep_kernel(const float* __restrict__ W_enc,
                                                   const float* __restrict__ W_gcn,
                                                   const float* __restrict__ W1,
                                                   const float* __restrict__ W2,
                                                   short* __restrict__ Wte,
                                                   short* __restrict__ Wtg,
                                                   short* __restrict__ Wt1,
                                                   short* __restrict__ W2t,
                                                   int* __restrict__ bcr) {
    int idx = blockIdx.x * 256 + threadIdx.x;
    if (idx < 16384) { int h = idx >> 7, k = idx & 127; Wte[idx] = f2bf(W_enc[k * 128 + h]); return; }
    idx -= 16384;
    if (idx < 16384) { int h = idx >> 7, k = idx & 127; Wtg[idx] = f2bf(W_gcn[k * 128 + h]); return; }
    idx -= 16384;
    if (idx < 32768) { int h = idx >> 7, k = idx & 127; Wt1[idx] = f2bf(W1[k * 256 + h]); return; }
    idx -= 32768;
    if (idx < 4096)  { int n = idx >> 8, k = idx & 255; W2t[idx] = (n < 10) ? f2bf(W2[k * 10 + n]) : (short)0; return; }
    idx -= 4096;
    if (idx < NB) bcr[idx] = 0;
}

// ---------- partition edges into 64-node dst-buckets (packed src | local_dst<<17) ----
__global__ __launch_bounds__(256) void part_kernel(const int* __restrict__ src,
                                                   const int* __restrict__ dst,
                                                   int* __restrict__ bcur,
                                                   int* __restrict__ part, int E) {
    __shared__ int cnt[NB];
    __shared__ int base[NB];
    for (int b = threadIdx.x; b < NB; b += 256) cnt[b] = 0;
    __syncthreads();
    const int e0 = blockIdx.x * CHUNK;
    const int e1 = min(e0 + CHUNK, E);
#pragma unroll 4
    for (int e = e0 + threadIdx.x; e < e1; e += 256)
        atomicAdd(&cnt[dst[e] >> 6], 1);
    __syncthreads();
    for (int b = threadIdx.x; b < NB; b += 256) {
        int c = cnt[b];
        base[b] = c ? atomicAdd(&bcur[b], c) : 0;
        cnt[b] = 0;  // reuse as local cursor
    }
    __syncthreads();
#pragma unroll 4
    for (int e = e0 + threadIdx.x; e < e1; e += 256) {
        int d = dst[e];
        int b = d >> 6;
        int idx = base[b] + atomicAdd(&cnt[b], 1);
        if (idx < BCAP) part[b * BCAP + idx] = src[e] | ((d & 63) << 17);
    }
}

// ---------- gemmA: degree scan + [relu(x@We+be)] -> LDS -> [(..@Wg)*dinv] -> xs ----
__global__ __launch_bounds__(256) void gemmA_kernel(const float* __restrict__ x,
                                                    const short* __restrict__ Wte,
                                                    const short* __restrict__ Wtg,
                                                    const float* __restrict__ b_enc,
                                                    const int* __restrict__ bcur,
                                                    const int* __restrict__ part,
                                                    short* __restrict__ xs) {
    __shared__ int deg_l[64];
    __shared__ short h_l[4][16][136];  // per-wave private 16x128 tiles (+pad)
    const int b = blockIdx.x;
    if (threadIdx.x < 64) deg_l[threadIdx.x] = 0;
    __syncthreads();
    const int cnt = min(bcur[b], BCAP);
    const int* p = part + (size_t)b * BCAP;
#pragma unroll 4
    for (int i = threadIdx.x; i < cnt; i += 256)
        atomicAdd(&deg_l[(p[i] >> 17) & 63], 1);

    const int wave = threadIdx.x >> 6;
    const int lane = threadIdx.x & 63;
    const int quad = lane >> 4;
    const int l16  = lane & 15;
    const int node0 = b * 64 + wave * 16;
    int nrow = node0 + l16;
    const bool valid = nrow < N_NODES;
    if (!valid) nrow = N_NODES - 1;

    // phase 1: h = relu(x @ W_enc + b_enc) -> LDS (bf16)
    f32x4 acc[8] = {};
#pragma unroll
    for (int kc = 0; kc < 4; ++kc) {
        const float* ap = x + (size_t)nrow * 128 + kc * 32 + quad * 8;
        float4 f0 = *reinterpret_cast<const float4*>(ap);
        float4 f1 = *reinterpret_cast<const float4*>(ap + 4);
        short8 xfrag;
        xfrag.s0 = f2bf(f0.x); xfrag.s1 = f2bf(f0.y); xfrag.s2 = f2bf(f0.z); xfrag.s3 = f2bf(f0.w);
        xfrag.s4 = f2bf(f1.x); xfrag.s5 = f2bf(f1.y); xfrag.s6 = f2bf(f1.z); xfrag.s7 = f2bf(f1.w);
#pragma unroll
        for (int t = 0; t < 8; ++t) {
            short8 wfrag = *reinterpret_cast<const short8*>(Wte + (size_t)(t * 16 + l16) * 128 + kc * 32 + quad * 8);
            acc[t] = __builtin_amdgcn_mfma_f32_16x16x32_bf16(wfrag, xfrag, acc[t], 0, 0, 0);
        }
    }
#pragma unroll
    for (int t = 0; t < 8; ++t) {
        short4v o;
#pragma unroll
        for (int r = 0; r < 4; ++r)
            ((short*)&o)[r] = f2bf(fmaxf(acc[t][r] + b_enc[t * 16 + quad * 4 + r], 0.f));
        *reinterpret_cast<short4v*>(&h_l[wave][l16][t * 16 + quad * 4]) = o;
    }
    __syncthreads();  // degree scan complete (h_l is wave-private)

    // phase 2: xs = (h @ W_gcn) * dinv[node]  (zero for pad rows)
    const float dvn = rsqrtf(1.f + (float)deg_l[wave * 16 + l16]);
    f32x4 acc2[8] = {};
#pragma unroll
    for (int kc = 0; kc < 4; ++kc) {
        short8 xfrag = *reinterpret_cast<const short8*>(&h_l[wave][l16][kc * 32 + quad * 8]);
#pragma unroll
        for (int t = 0; t < 8; ++t) {
            short8 wfrag = *reinterpret_cast<const short8*>(Wtg + (size_t)(t * 16 + l16) * 128 + kc * 32 + quad * 8);
            acc2[t] = __builtin_amdgcn_mfma_f32_16x16x32_bf16(wfrag, xfrag, acc2[t], 0, 0, 0);
        }
    }
    const int srow = node0 + l16;  // unclamped
#pragma unroll
    for (int t = 0; t < 8; ++t) {
        short4v o;
#pragma unroll
        for (int r = 0; r < 4; ++r)
            ((short*)&o)[r] = valid ? f2bf(acc2[t][r] * dvn) : (short)0;
        *reinterpret_cast<short4v*>(xs + (size_t)(valid ? srow : srow) * 128 + t * 16 + quad * 4) = o;
    }
}

// ---------- agg: h2 = relu(dv * (sum_edges xs[src] + xs[node]) + b_gcn) ----------
__global__ __launch_bounds__(256) void agg_kernel(const short* __restrict__ xs,
                                                  const int* __restrict__ bcur,
                                                  const int* __restrict__ part,
                                                  const float* __restrict__ bg,
                                                  short* __restrict__ h2) {
    __shared__ int csr_l[64 * LCAP];   // 20480 B
    __shared__ int cur[64];
    const int b = blockIdx.x;
    if (threadIdx.x < 64) cur[threadIdx.x] = 0;
    __syncthreads();
    const int cnt = min(bcur[b], BCAP);
    const int* p = part + (size_t)b * BCAP;
#pragma unroll 4
    for (int i = threadIdx.x; i < cnt; i += 256) {
        int v = p[i];
        int ld = (v >> 17) & 63;
        int pos = atomicAdd(&cur[ld], 1);
        if (pos < LCAP) csr_l[ld * LCAP + pos] = v & 0x1FFFF;
    }
    __syncthreads();

    const int wave = threadIdx.x >> 6;
    const int lane = threadIdx.x & 63;
    const unsigned* xsu = reinterpret_cast<const unsigned*>(xs);
    for (int t = 0; t < 16; ++t) {
        const int ld = wave * 16 + t;
        const int node = b * 64 + ld;
        if (node >= N_NODES) break;  // wave-uniform

        const int dtrue = cur[ld];
        const int d = min(dtrue, LCAP);
        const float dv = rsqrtf(1.f + (float)dtrue);

        // lane-parallel src prefetch; pad with zero-row PADN
        int s0 = PADN, s1 = PADN;
        if (lane < d)      s0 = csr_l[ld * LCAP + lane];
        if (lane + 64 < d) s1 = csr_l[ld * LCAP + lane + 64];

        float ax = 0.f, ay = 0.f;
        const int dpad = (d + 7) & ~7;
        const int n0 = dpad < 64 ? dpad : 64;
        for (int j0 = 0; j0 < n0; j0 += 8) {
#pragma unroll
            for (int u = 0; u < 8; ++u) {
                int sj = __shfl(s0, j0 + u, 64);
                unsigned v = xsu[((size_t)sj << 6) + lane];
                ax += lo_bf(v);
                ay += hi_bf(v);
            }
        }
        for (int j0 = 64; j0 < dpad; j0 += 8) {
#pragma unroll
            for (int u = 0; u < 8; ++u) {
                int sj = __shfl(s1, j0 + u - 64, 64);
                unsigned v = xsu[((size_t)sj << 6) + lane];
                ax += lo_bf(v);
                ay += hi_bf(v);
            }
        }
        // self-loop (xs[node] already carries dinv[node])
        unsigned vs = xsu[((size_t)node << 6) + lane];
        ax += lo_bf(vs);
        ay += hi_bf(vs);
        ax = fmaxf(fmaf(ax, dv, bg[lane * 2 + 0]), 0.f);
        ay = fmaxf(fmaf(ay, dv, bg[lane * 2 + 1]), 0.f);
        unsigned o = (unsigned)(unsigned short)f2bf(ax) | ((unsigned)(unsigned short)f2bf(ay) << 16);
        *(reinterpret_cast<unsigned*>(h2 + ((size_t)node << 7)) + lane) = o;
    }
}

// ---------- gemmB: hq = relu(h2@W1+b1) -> LDS -> q = hq@W2 + b2 ----------
__global__ __launch_bounds__(256) void gemmB_kernel(const short* __restrict__ h2,
                                                    const short* __restrict__ Wt1,
                                                    const short* __restrict__ W2t,
                                                    const float* __restrict__ b1,
                                                    const float* __restrict__ b2,
                                                    float* __restrict__ q) {
    __shared__ short hq_l[4][16][264];  // per-wave private 16x256 tiles (+pad)
    const int wave = threadIdx.x >> 6;
    const int lane = threadIdx.x & 63;
    const int quad = lane >> 4;
    const int l16  = lane & 15;
    const int node0 = blockIdx.x * 64 + wave * 16;
    int nrow = node0 + l16;
    if (nrow >= N_NODES) nrow = N_NODES - 1;

    f32x4 acc[16] = {};
#pragma unroll
    for (int kc = 0; kc < 4; ++kc) {
        short8 xfrag = *reinterpret_cast<const short8*>(h2 + (size_t)nrow * 128 + kc * 32 + quad * 8);
#pragma unroll
        for (int t = 0; t < 16; ++t) {
            short8 wfrag = *reinterpret_cast<const short8*>(Wt1 + (size_t)(t * 16 + l16) * 128 + kc * 32 + quad * 8);
            acc[t] = __builtin_amdgcn_mfma_f32_16x16x32_bf16(wfrag, xfrag, acc[t], 0, 0, 0);
        }
    }
#pragma unroll
    for (int t = 0; t < 16; ++t) {
        short4v o;
#pragma unroll
        for (int r = 0; r < 4; ++r)
            ((short*)&o)[r] = f2bf(fmaxf(acc[t][r] + b1[t * 16 + quad * 4 + r], 0.f));
        *reinterpret_cast<short4v*>(&hq_l[wave][l16][t * 16 + quad * 4]) = o;
    }
    // wave-private tile: ds_write -> ds_read ordered by lgkmcnt, no barrier needed

    f32x4 a2 = {};
#pragma unroll
    for (int kc = 0; kc < 8; ++kc) {
        short8 afrag = *reinterpret_cast<const short8*>(&hq_l[wave][l16][kc * 32 + quad * 8]);
        short8 bfrag = *reinterpret_cast<const short8*>(W2t + (size_t)l16 * 256 + kc * 32 + quad * 8);
        a2 = __builtin_amdgcn_mfma_f32_16x16x32_bf16(afrag, bfrag, a2, 0, 0, 0);
    }
    if (l16 < 10) {
        float bv = b2[l16];
#pragma unroll
        for (int r = 0; r < 4; ++r) {
            int nd = node0 + quad * 4 + r;
            if (nd < N_NODES) q[(size_t)nd * 10 + l16] = a2[r] + bv;
        }
    }
}

extern "C" void kernel_launch(void* const* d_in, const int* in_sizes, int n_in,
                              void* d_out, int out_size, void* d_ws, size_t ws_size,
                              hipStream_t stream) {
    const float* x     = (const float*)d_in[0];
    const int*   ei    = (const int*)d_in[1];
    const float* W_enc = (const float*)d_in[2];
    const float* b_enc = (const float*)d_in[3];
    const float* W_gcn = (const float*)d_in[4];
    const float* b_gcn = (const float*)d_in[5];
    const float* W1    = (const float*)d_in[6];
    const float* b1    = (const float*)d_in[7];
    const float* W2    = (const float*)d_in[8];
    const float* b2    = (const float*)d_in[9];
    float* q = (float*)d_out;

    const int E = in_sizes[1] / 2;
    const int* srcv = ei;
    const int* dstv = ei + E;

    // workspace layout (bytes)
    char* ws = (char*)d_ws;
    const size_t XSB = (size_t)(NB * 64) * 128 * sizeof(short);  // 25,608,192 (incl. pad rows)
    short* xs  = (short*)(ws);
    short* h2  = (short*)(ws + XSB);
    int*   part= (int*)  (ws + 2 * XSB);                         // 16,005,120
    char*  tail = ws + 2 * XSB + (size_t)NB * BCAP * sizeof(int);
    int*   bcr = (int*)(tail);                                   // 8 KB slot
    short* Wte = (short*)(tail + 8192);
    short* Wtg = (short*)(tail + 8192 + 32768);
    short* Wt1 = (short*)(tail + 8192 + 65536);
    short* W2t = (short*)(tail + 8192 + 131072);
    // end ~= 67.4 MB

    prep_kernel<<<279, 256, 0, stream>>>(W_enc, W_gcn, W1, W2, Wte, Wtg, Wt1, W2t, bcr);
    part_kernel<<<(E + CHUNK - 1) / CHUNK, 256, 0, stream>>>(srcv, dstv, bcr, part, E);
    gemmA_kernel<<<NB, 256, 0, stream>>>(x, Wte, Wtg, b_enc, bcr, part, xs);
    agg_kernel<<<NB, 256, 0, stream>>>(xs, bcr, part, b_gcn, h2);
    gemmB_kernel<<<NB, 256, 0, stream>>>(h2, Wt1, W2t, b1, b2, q);
}

// Round 6
// 407.820 us; speedup vs baseline: 3.1183x; 1.1370x over previous
//
#include <hip/hip_runtime.h>

#define N_NODES 100000
constexpr int F     = 128;
constexpr int NB    = (N_NODES + 63) / 64;  // 1563 buckets of 64 dst-nodes
constexpr int BCAP  = 2560;                 // bucket capacity (mean 2048, +11 sigma)
constexpr int LCAP  = 80;                   // per-node LDS CSR cap (max in-deg ~65)
constexpr int CHUNK = 8192;                 // edges per partition block (391 blocks)
constexpr int PADN  = N_NODES;              // zero-row index for edge-list padding

typedef __attribute__((ext_vector_type(8))) short short8;   // 8 bf16 (4 VGPRs)
typedef __attribute__((ext_vector_type(4))) float f32x4;    // MFMA C/D
typedef __attribute__((ext_vector_type(4))) short short4v;

__device__ inline short f2bf(float v) {
    union { float f; unsigned u; } x; x.f = v;
    unsigned r = (x.u + 0x7fff + ((x.u >> 16) & 1)) >> 16;  // round-nearest-even
    return (short)r;
}
__device__ inline float lo_bf(unsigned v) {  // low bf16 -> f32
    union { unsigned u; float f; } x; x.u = v << 16; return x.f;
}
__device__ inline float hi_bf(unsigned v) {  // high bf16 -> f32
    union { unsigned u; float f; } x; x.u = v & 0xffff0000u; return x.f;
}

// ---------- weight prep (transpose->bf16) + bcr zeroing ----------
__global__ __launch_bounds__(256) void prep_kernel(const float* __restrict__ W_enc,
                                                   const float* __restrict__ W_gcn,
                                                   const float* __restrict__ W1,
                                                   const float* __restrict__ W2,
                                                   short* __restrict__ Wte,
                                                   short* __restrict__ Wtg,
                                                   short* __restrict__ Wt1,
                                                   short* __restrict__ W2t,
                                                   int* __restrict__ bcr) {
    int idx = blockIdx.x * 256 + threadIdx.x;
    if (idx < 16384) { int h = idx >> 7, k = idx & 127; Wte[idx] = f2bf(W_enc[k * 128 + h]); return; }
    idx -= 16384;
    if (idx < 16384) { int h = idx >> 7, k = idx & 127; Wtg[idx] = f2bf(W_gcn[k * 128 + h]); return; }
    idx -= 16384;
    if (idx < 32768) { int h = idx >> 7, k = idx & 127; Wt1[idx] = f2bf(W1[k * 256 + h]); return; }
    idx -= 32768;
    if (idx < 4096)  { int n = idx >> 8, k = idx & 255; W2t[idx] = (n < 10) ? f2bf(W2[k * 10 + n]) : (short)0; return; }
    idx -= 4096;
    if (idx < NB) bcr[idx] = 0;
}

// ---------- partition edges into 64-node dst-buckets (packed src | local_dst<<17) ----
__global__ __launch_bounds__(512) void part_kernel(const int* __restrict__ src,
                                                   const int* __restrict__ dst,
                                                   int* __restrict__ bcur,
                                                   int* __restrict__ part, int E) {
    __shared__ int cnt[NB];
    __shared__ int base[NB];
    for (int b = threadIdx.x; b < NB; b += 512) cnt[b] = 0;
    __syncthreads();
    const int e0 = blockIdx.x * CHUNK;
    const int e1 = min(e0 + CHUNK, E);
#pragma unroll 4
    for (int e = e0 + threadIdx.x; e < e1; e += 512)
        atomicAdd(&cnt[dst[e] >> 6], 1);
    __syncthreads();
    for (int b = threadIdx.x; b < NB; b += 512) {
        int c = cnt[b];
        base[b] = c ? atomicAdd(&bcur[b], c) : 0;
        cnt[b] = 0;  // reuse as local cursor
    }
    __syncthreads();
#pragma unroll 4
    for (int e = e0 + threadIdx.x; e < e1; e += 512) {
        int d = dst[e];
        int b = d >> 6;
        int idx = base[b] + atomicAdd(&cnt[b], 1);
        if (idx < BCAP) part[b * BCAP + idx] = src[e] | ((d & 63) << 17);
    }
}

// ---------- gemmA: degree scan + [relu(x@We+be)] -> LDS -> [(..@Wg)*dinv] -> xs ----
__global__ __launch_bounds__(256) void gemmA_kernel(const float* __restrict__ x,
                                                    const short* __restrict__ Wte,
                                                    const short* __restrict__ Wtg,
                                                    const float* __restrict__ b_enc,
                                                    const int* __restrict__ bcur,
                                                    const int* __restrict__ part,
                                                    short* __restrict__ xs) {
    __shared__ int deg_l[64];
    __shared__ short h_l[4][16][136];  // per-wave private 16x128 tiles (+pad)
    const int b = blockIdx.x;
    if (threadIdx.x < 64) deg_l[threadIdx.x] = 0;
    __syncthreads();
    const int cnt = min(bcur[b], BCAP);
    const int* p = part + (size_t)b * BCAP;
#pragma unroll 4
    for (int i = threadIdx.x; i < cnt; i += 256)
        atomicAdd(&deg_l[(p[i] >> 17) & 63], 1);

    const int wave = threadIdx.x >> 6;
    const int lane = threadIdx.x & 63;
    const int quad = lane >> 4;
    const int l16  = lane & 15;
    const int node0 = b * 64 + wave * 16;
    int nrow = node0 + l16;
    const bool valid = nrow < N_NODES;
    if (!valid) nrow = N_NODES - 1;

    // phase 1: h = relu(x @ W_enc + b_enc) -> LDS (bf16)
    f32x4 acc[8] = {};
#pragma unroll
    for (int kc = 0; kc < 4; ++kc) {
        const float* ap = x + (size_t)nrow * 128 + kc * 32 + quad * 8;
        float4 f0 = *reinterpret_cast<const float4*>(ap);
        float4 f1 = *reinterpret_cast<const float4*>(ap + 4);
        short8 xfrag;
        xfrag.s0 = f2bf(f0.x); xfrag.s1 = f2bf(f0.y); xfrag.s2 = f2bf(f0.z); xfrag.s3 = f2bf(f0.w);
        xfrag.s4 = f2bf(f1.x); xfrag.s5 = f2bf(f1.y); xfrag.s6 = f2bf(f1.z); xfrag.s7 = f2bf(f1.w);
#pragma unroll
        for (int t = 0; t < 8; ++t) {
            short8 wfrag = *reinterpret_cast<const short8*>(Wte + (size_t)(t * 16 + l16) * 128 + kc * 32 + quad * 8);
            acc[t] = __builtin_amdgcn_mfma_f32_16x16x32_bf16(wfrag, xfrag, acc[t], 0, 0, 0);
        }
    }
#pragma unroll
    for (int t = 0; t < 8; ++t) {
        short4v o;
#pragma unroll
        for (int r = 0; r < 4; ++r)
            ((short*)&o)[r] = f2bf(fmaxf(acc[t][r] + b_enc[t * 16 + quad * 4 + r], 0.f));
        *reinterpret_cast<short4v*>(&h_l[wave][l16][t * 16 + quad * 4]) = o;
    }
    __syncthreads();  // degree scan complete (h_l is wave-private)

    // phase 2: xs = (h @ W_gcn) * dinv[node]  (zero for pad rows)
    const float dvn = rsqrtf(1.f + (float)deg_l[wave * 16 + l16]);
    f32x4 acc2[8] = {};
#pragma unroll
    for (int kc = 0; kc < 4; ++kc) {
        short8 xfrag = *reinterpret_cast<const short8*>(&h_l[wave][l16][kc * 32 + quad * 8]);
#pragma unroll
        for (int t = 0; t < 8; ++t) {
            short8 wfrag = *reinterpret_cast<const short8*>(Wtg + (size_t)(t * 16 + l16) * 128 + kc * 32 + quad * 8);
            acc2[t] = __builtin_amdgcn_mfma_f32_16x16x32_bf16(wfrag, xfrag, acc2[t], 0, 0, 0);
        }
    }
    const int srow = node0 + l16;
#pragma unroll
    for (int t = 0; t < 8; ++t) {
        short4v o;
#pragma unroll
        for (int r = 0; r < 4; ++r)
            ((short*)&o)[r] = valid ? f2bf(acc2[t][r] * dvn) : (short)0;
        *reinterpret_cast<short4v*>(xs + (size_t)srow * 128 + t * 16 + quad * 4) = o;
    }
}

// ---------- agg: h2 = relu(dv * (sum_edges xs[src] + xs[node]) + b_gcn) ----------
// half-wave split: lanes 0-31 even edges, 32-63 odd edges; 8 B/lane row halves;
// src index via LDS broadcast read (no shfl); combine halves once per node.
__global__ __launch_bounds__(256) void agg_kernel(const short* __restrict__ xs,
                                                  const int* __restrict__ bcur,
                                                  const int* __restrict__ part,
                                                  const float* __restrict__ bg,
                                                  short* __restrict__ h2) {
    __shared__ int csr_l[64 * LCAP];   // 20480 B
    __shared__ int cur[64];
    const int b = blockIdx.x;
    const int tid = threadIdx.x;
    if (tid < 64) cur[tid] = 0;
    __syncthreads();
    const int cnt = min(bcur[b], BCAP);
    const int* p = part + (size_t)b * BCAP;
#pragma unroll 4
    for (int i = tid; i < cnt; i += 256) {
        int v = p[i];
        int ld = (v >> 17) & 63;
        int pos = atomicAdd(&cur[ld], 1);
        if (pos < LCAP) csr_l[ld * LCAP + pos] = v & 0x1FFFF;
    }
    __syncthreads();
    // pad each node's list to x8 with PADN (zero row) -> branch-free inner loop
    if (tid < 64) {
        int d = min(cur[tid], LCAP);
        int dp = (d + 7) & ~7;
        for (int k = d; k < dp; ++k) csr_l[tid * LCAP + k] = PADN;
    }
    __syncthreads();

    const int wave = tid >> 6;
    const int lane = tid & 63;
    const int half = lane >> 5;   // 0: even edges, 1: odd edges
    const int fl   = lane & 31;   // feature group of 4 (8 B)
    const uint2* xs2 = reinterpret_cast<const uint2*>(xs);
    const float4 bg4 = reinterpret_cast<const float4*>(bg)[fl];

    for (int t = 0; t < 16; ++t) {
        const int ld = wave * 16 + t;
        const int node = b * 64 + ld;
        if (node >= N_NODES) break;  // wave-uniform

        const int dtrue = cur[ld];
        const int dpad = (min(dtrue, LCAP) + 7) & ~7;
        const float dv = rsqrtf(1.f + (float)dtrue);
        const int* cl = csr_l + ld * LCAP;

        float a0 = 0.f, a1 = 0.f, a2 = 0.f, a3 = 0.f;
        for (int j = 0; j < dpad; j += 8) {
#pragma unroll
            for (int u = 0; u < 4; ++u) {
                int sj = cl[j + u * 2 + half];                 // 2-addr LDS broadcast
                uint2 v = xs2[((size_t)sj << 5) + fl];         // 8 B of 256 B row
                a0 += lo_bf(v.x); a1 += hi_bf(v.x);
                a2 += lo_bf(v.y); a3 += hi_bf(v.y);
            }
        }
        // combine even/odd halves
        a0 += __shfl_xor(a0, 32, 64);
        a1 += __shfl_xor(a1, 32, 64);
        a2 += __shfl_xor(a2, 32, 64);
        a3 += __shfl_xor(a3, 32, 64);
        // self-loop (xs[node] already carries dinv[node])
        uint2 vs = xs2[((size_t)node << 5) + fl];
        a0 += lo_bf(vs.x); a1 += hi_bf(vs.x);
        a2 += lo_bf(vs.y); a3 += hi_bf(vs.y);
        a0 = fmaxf(fmaf(a0, dv, bg4.x), 0.f);
        a1 = fmaxf(fmaf(a1, dv, bg4.y), 0.f);
        a2 = fmaxf(fmaf(a2, dv, bg4.z), 0.f);
        a3 = fmaxf(fmaf(a3, dv, bg4.w), 0.f);
        if (lane < 32) {
            uint2 o;
            o.x = (unsigned)(unsigned short)f2bf(a0) | ((unsigned)(unsigned short)f2bf(a1) << 16);
            o.y = (unsigned)(unsigned short)f2bf(a2) | ((unsigned)(unsigned short)f2bf(a3) << 16);
            reinterpret_cast<uint2*>(h2)[((size_t)node << 5) + fl] = o;
        }
    }
}

// ---------- gemmB: hq = relu(h2@W1+b1) -> LDS -> q = hq@W2 + b2 ----------
__global__ __launch_bounds__(256) void gemmB_kernel(const short* __restrict__ h2,
                                                    const short* __restrict__ Wt1,
                                                    const short* __restrict__ W2t,
                                                    const float* __restrict__ b1,
                                                    const float* __restrict__ b2,
                                                    float* __restrict__ q) {
    __shared__ short hq_l[4][16][264];  // per-wave private 16x256 tiles (+pad)
    const int wave = threadIdx.x >> 6;
    const int lane = threadIdx.x & 63;
    const int quad = lane >> 4;
    const int l16  = lane & 15;
    const int node0 = blockIdx.x * 64 + wave * 16;
    int nrow = node0 + l16;
    if (nrow >= N_NODES) nrow = N_NODES - 1;

    f32x4 acc[16] = {};
#pragma unroll
    for (int kc = 0; kc < 4; ++kc) {
        short8 xfrag = *reinterpret_cast<const short8*>(h2 + (size_t)nrow * 128 + kc * 32 + quad * 8);
#pragma unroll
        for (int t = 0; t < 16; ++t) {
            short8 wfrag = *reinterpret_cast<const short8*>(Wt1 + (size_t)(t * 16 + l16) * 128 + kc * 32 + quad * 8);
            acc[t] = __builtin_amdgcn_mfma_f32_16x16x32_bf16(wfrag, xfrag, acc[t], 0, 0, 0);
        }
    }
#pragma unroll
    for (int t = 0; t < 16; ++t) {
        short4v o;
#pragma unroll
        for (int r = 0; r < 4; ++r)
            ((short*)&o)[r] = f2bf(fmaxf(acc[t][r] + b1[t * 16 + quad * 4 + r], 0.f));
        *reinterpret_cast<short4v*>(&hq_l[wave][l16][t * 16 + quad * 4]) = o;
    }
    // wave-private tile: ds_write -> ds_read ordered by lgkmcnt, no barrier needed

    f32x4 a2 = {};
#pragma unroll
    for (int kc = 0; kc < 8; ++kc) {
        short8 afrag = *reinterpret_cast<const short8*>(&hq_l[wave][l16][kc * 32 + quad * 8]);
        short8 bfrag = *reinterpret_cast<const short8*>(W2t + (size_t)l16 * 256 + kc * 32 + quad * 8);
        a2 = __builtin_amdgcn_mfma_f32_16x16x32_bf16(afrag, bfrag, a2, 0, 0, 0);
    }
    if (l16 < 10) {
        float bv = b2[l16];
#pragma unroll
        for (int r = 0; r < 4; ++r) {
            int nd = node0 + quad * 4 + r;
            if (nd < N_NODES) q[(size_t)nd * 10 + l16] = a2[r] + bv;
        }
    }
}

extern "C" void kernel_launch(void* const* d_in, const int* in_sizes, int n_in,
                              void* d_out, int out_size, void* d_ws, size_t ws_size,
                              hipStream_t stream) {
    const float* x     = (const float*)d_in[0];
    const int*   ei    = (const int*)d_in[1];
    const float* W_enc = (const float*)d_in[2];
    const float* b_enc = (const float*)d_in[3];
    const float* W_gcn = (const float*)d_in[4];
    const float* b_gcn = (const float*)d_in[5];
    const float* W1    = (const float*)d_in[6];
    const float* b1    = (const float*)d_in[7];
    const float* W2    = (const float*)d_in[8];
    const float* b2    = (const float*)d_in[9];
    float* q = (float*)d_out;

    const int E = in_sizes[1] / 2;
    const int* srcv = ei;
    const int* dstv = ei + E;

    // workspace layout (bytes)
    char* ws = (char*)d_ws;
    const size_t XSB = (size_t)(NB * 64) * 128 * sizeof(short);  // 25,608,192 (incl. pad rows)
    short* xs  = (short*)(ws);
    short* h2  = (short*)(ws + XSB);
    int*   part= (int*)  (ws + 2 * XSB);                         // 16,005,120
    char*  tail = ws + 2 * XSB + (size_t)NB * BCAP * sizeof(int);
    int*   bcr = (int*)(tail);                                   // 8 KB slot
    short* Wte = (short*)(tail + 8192);
    short* Wtg = (short*)(tail + 8192 + 32768);
    short* Wt1 = (short*)(tail + 8192 + 65536);
    short* W2t = (short*)(tail + 8192 + 131072);
    // end ~= 67.4 MB

    prep_kernel<<<279, 256, 0, stream>>>(W_enc, W_gcn, W1, W2, Wte, Wtg, Wt1, W2t, bcr);
    part_kernel<<<(E + CHUNK - 1) / CHUNK, 512, 0, stream>>>(srcv, dstv, bcr, part, E);
    gemmA_kernel<<<NB, 256, 0, stream>>>(x, Wte, Wtg, b_enc, bcr, part, xs);
    agg_kernel<<<NB, 256, 0, stream>>>(xs, bcr, part, b_gcn, h2);
    gemmB_kernel<<<NB, 256, 0, stream>>>(h2, Wt1, W2t, b1, b2, q);
}

// Round 7
// 402.264 us; speedup vs baseline: 3.1613x; 1.0138x over previous
//
#include <hip/hip_runtime.h>

#define N_NODES 100000
constexpr int F     = 128;
constexpr int NB    = (N_NODES + 63) / 64;  // 1563 buckets of 64 dst-nodes
constexpr int BCAP  = 2560;                 // bucket capacity (mean 2048, +11 sigma)
constexpr int LCAP  = 80;                   // per-node LDS CSR cap (max in-deg ~65)
constexpr int CHUNK = 8192;                 // edges per partition block (391 blocks)
constexpr int PADN  = N_NODES;              // zero-row index for edge-list padding

typedef __attribute__((ext_vector_type(8))) short short8;   // 8 bf16 (4 VGPRs)
typedef __attribute__((ext_vector_type(4))) float f32x4;    // MFMA C/D
typedef __attribute__((ext_vector_type(4))) short short4v;
typedef __attribute__((ext_vector_type(4))) unsigned uint4v;

__device__ inline short f2bf(float v) {
    union { float f; unsigned u; } x; x.f = v;
    unsigned r = (x.u + 0x7fff + ((x.u >> 16) & 1)) >> 16;  // round-nearest-even
    return (short)r;
}
__device__ inline float lo_bf(unsigned v) {
    union { unsigned u; float f; } x; x.u = v << 16; return x.f;
}
__device__ inline float hi_bf(unsigned v) {
    union { unsigned u; float f; } x; x.u = v & 0xffff0000u; return x.f;
}

// ---------- weight prep (transpose->bf16) + bcr zeroing ----------
__global__ __launch_bounds__(256) void prep_kernel(const float* __restrict__ W_enc,
                                                   const float* __restrict__ W_gcn,
                                                   const float* __restrict__ W1,
                                                   const float* __restrict__ W2,
                                                   short* __restrict__ Wte,
                                                   short* __restrict__ Wtg,
                                                   short* __restrict__ Wt1,
                                                   short* __restrict__ W2t,
                                                   int* __restrict__ bcr) {
    int idx = blockIdx.x * 256 + threadIdx.x;
    if (idx < 16384) { int h = idx >> 7, k = idx & 127; Wte[idx] = f2bf(W_enc[k * 128 + h]); return; }
    idx -= 16384;
    if (idx < 16384) { int h = idx >> 7, k = idx & 127; Wtg[idx] = f2bf(W_gcn[k * 128 + h]); return; }
    idx -= 16384;
    if (idx < 32768) { int h = idx >> 7, k = idx & 127; Wt1[idx] = f2bf(W1[k * 256 + h]); return; }
    idx -= 32768;
    if (idx < 4096)  { int n = idx >> 8, k = idx & 255; W2t[idx] = (n < 10) ? f2bf(W2[k * 10 + n]) : (short)0; return; }
    idx -= 4096;
    if (idx < NB) bcr[idx] = 0;
}

// ---------- partition edges into 64-node dst-buckets (packed src | local_dst<<17) ----
__global__ __launch_bounds__(512) void part_kernel(const int* __restrict__ src,
                                                   const int* __restrict__ dst,
                                                   int* __restrict__ bcur,
                                                   int* __restrict__ part, int E) {
    __shared__ int cnt[NB];
    __shared__ int base[NB];
    for (int b = threadIdx.x; b < NB; b += 512) cnt[b] = 0;
    __syncthreads();
    const int e0 = blockIdx.x * CHUNK;
    const int e1 = min(e0 + CHUNK, E);
#pragma unroll 4
    for (int e = e0 + threadIdx.x; e < e1; e += 512)
        atomicAdd(&cnt[dst[e] >> 6], 1);
    __syncthreads();
    for (int b = threadIdx.x; b < NB; b += 512) {
        int c = cnt[b];
        base[b] = c ? atomicAdd(&bcur[b], c) : 0;
        cnt[b] = 0;  // reuse as local cursor
    }
    __syncthreads();
#pragma unroll 4
    for (int e = e0 + threadIdx.x; e < e1; e += 512) {
        int d = dst[e];
        int b = d >> 6;
        int idx = base[b] + atomicAdd(&cnt[b], 1);
        if (idx < BCAP) part[b * BCAP + idx] = src[e] | ((d & 63) << 17);
    }
}

// ---------- gemmA: degree scan + [relu(x@We+be)] -> LDS -> [(..@Wg)*dinv] -> xs ----
__global__ __launch_bounds__(256) void gemmA_kernel(const float* __restrict__ x,
                                                    const short* __restrict__ Wte,
                                                    const short* __restrict__ Wtg,
                                                    const float* __restrict__ b_enc,
                                                    const int* __restrict__ bcur,
                                                    const int* __restrict__ part,
                                                    short* __restrict__ xs) {
    __shared__ int deg_l[64];
    __shared__ short h_l[4][16][136];  // per-wave private 16x128 tiles (+pad)
    const int b = blockIdx.x;
    if (threadIdx.x < 64) deg_l[threadIdx.x] = 0;
    __syncthreads();
    const int cnt = min(bcur[b], BCAP);
    const int* p = part + (size_t)b * BCAP;
#pragma unroll 4
    for (int i = threadIdx.x; i < cnt; i += 256)
        atomicAdd(&deg_l[(p[i] >> 17) & 63], 1);

    const int wave = threadIdx.x >> 6;
    const int lane = threadIdx.x & 63;
    const int quad = lane >> 4;
    const int l16  = lane & 15;
    const int node0 = b * 64 + wave * 16;
    int nrow = node0 + l16;
    const bool valid = nrow < N_NODES;
    if (!valid) nrow = N_NODES - 1;

    // phase 1: h = relu(x @ W_enc + b_enc) -> LDS (bf16)
    f32x4 acc[8] = {};
#pragma unroll
    for (int kc = 0; kc < 4; ++kc) {
        const float* ap = x + (size_t)nrow * 128 + kc * 32 + quad * 8;
        float4 f0 = *reinterpret_cast<const float4*>(ap);
        float4 f1 = *reinterpret_cast<const float4*>(ap + 4);
        short8 xfrag;
        xfrag.s0 = f2bf(f0.x); xfrag.s1 = f2bf(f0.y); xfrag.s2 = f2bf(f0.z); xfrag.s3 = f2bf(f0.w);
        xfrag.s4 = f2bf(f1.x); xfrag.s5 = f2bf(f1.y); xfrag.s6 = f2bf(f1.z); xfrag.s7 = f2bf(f1.w);
#pragma unroll
        for (int t = 0; t < 8; ++t) {
            short8 wfrag = *reinterpret_cast<const short8*>(Wte + (size_t)(t * 16 + l16) * 128 + kc * 32 + quad * 8);
            acc[t] = __builtin_amdgcn_mfma_f32_16x16x32_bf16(wfrag, xfrag, acc[t], 0, 0, 0);
        }
    }
#pragma unroll
    for (int t = 0; t < 8; ++t) {
        short4v o;
#pragma unroll
        for (int r = 0; r < 4; ++r)
            ((short*)&o)[r] = f2bf(fmaxf(acc[t][r] + b_enc[t * 16 + quad * 4 + r], 0.f));
        *reinterpret_cast<short4v*>(&h_l[wave][l16][t * 16 + quad * 4]) = o;
    }
    __syncthreads();  // degree scan complete (h_l is wave-private)

    // phase 2: xs = (h @ W_gcn) * dinv[node]  (zero for pad rows)
    const float dvn = rsqrtf(1.f + (float)deg_l[wave * 16 + l16]);
    f32x4 acc2[8] = {};
#pragma unroll
    for (int kc = 0; kc < 4; ++kc) {
        short8 xfrag = *reinterpret_cast<const short8*>(&h_l[wave][l16][kc * 32 + quad * 8]);
#pragma unroll
        for (int t = 0; t < 8; ++t) {
            short8 wfrag = *reinterpret_cast<const short8*>(Wtg + (size_t)(t * 16 + l16) * 128 + kc * 32 + quad * 8);
            acc2[t] = __builtin_amdgcn_mfma_f32_16x16x32_bf16(wfrag, xfrag, acc2[t], 0, 0, 0);
        }
    }
    const int srow = node0 + l16;
#pragma unroll
    for (int t = 0; t < 8; ++t) {
        short4v o;
#pragma unroll
        for (int r = 0; r < 4; ++r)
            ((short*)&o)[r] = valid ? f2bf(acc2[t][r] * dvn) : (short)0;
        *reinterpret_cast<short4v*>(xs + (size_t)srow * 128 + t * 16 + quad * 4) = o;
    }
}

// ---------- fused agg + MLP:  q = (relu(h2@W1+b1)) @ W2 + b2,
//            h2 = relu(dv*(sum xs[src] + xs[node]) + b_gcn) built in LDS ----------
// gather: 4 lane-groups of 16, one edge per group, 16 B/lane (full 256 B row per group).
__global__ __launch_bounds__(256, 3) void aggB_kernel(const short* __restrict__ xs,
                                                      const int* __restrict__ bcur,
                                                      const int* __restrict__ part,
                                                      const float* __restrict__ bg,
                                                      const short* __restrict__ Wt1,
                                                      const short* __restrict__ W2t,
                                                      const float* __restrict__ b1,
                                                      const float* __restrict__ b2,
                                                      float* __restrict__ q) {
    // LDS: region A = csr(20480)+cur(256) during gather, hq_l(33792) during MLP
    __shared__ char smemA[64 * LCAP * 4 > 4 * 16 * 264 * 2 ? 64 * LCAP * 4 : 4 * 16 * 264 * 2 + 256];
    __shared__ short h2_l[4][16][136];  // 17408 B, per-wave private
    int* csr_l = (int*)smemA;
    int* cur   = (int*)(smemA + 64 * LCAP * 4);

    const int b = blockIdx.x;
    const int tid = threadIdx.x;
    if (tid < 64) cur[tid] = 0;
    __syncthreads();
    const int cnt = min(bcur[b], BCAP);
    const int* p = part + (size_t)b * BCAP;
#pragma unroll 4
    for (int i = tid; i < cnt; i += 256) {
        int v = p[i];
        int ld = (v >> 17) & 63;
        int pos = atomicAdd(&cur[ld], 1);
        if (pos < LCAP) csr_l[ld * LCAP + pos] = v & 0x1FFFF;
    }
    __syncthreads();
    if (tid < 64) {  // pad each list to x8 with PADN (zero row)
        int d = min(cur[tid], LCAP);
        int dp = (d + 7) & ~7;
        for (int k = d; k < dp; ++k) csr_l[tid * LCAP + k] = PADN;
    }
    __syncthreads();

    const int wave = tid >> 6;
    const int lane = tid & 63;
    const int g    = lane >> 4;   // edge group
    const int l16  = lane & 15;   // 16 B feature slot
    const uint4v* xs4 = reinterpret_cast<const uint4v*>(xs);
    const float4 bgA = reinterpret_cast<const float4*>(bg)[l16 * 2];
    const float4 bgB = reinterpret_cast<const float4*>(bg)[l16 * 2 + 1];

    // ---- phase 1: gather -> h2 tile in LDS ----
    for (int t = 0; t < 16; ++t) {
        const int ld = wave * 16 + t;
        const int node = b * 64 + ld;
        if (node >= N_NODES) break;  // wave-uniform

        const int dtrue = cur[ld];
        const int dpad = (min(dtrue, LCAP) + 7) & ~7;
        const float dv = rsqrtf(1.f + (float)dtrue);
        const int* cl = csr_l + ld * LCAP;

        float a0 = 0.f, a1 = 0.f, a2 = 0.f, a3 = 0.f, a4 = 0.f, a5 = 0.f, a6 = 0.f, a7 = 0.f;
        for (int j = 0; j < dpad; j += 8) {
#pragma unroll
            for (int u = 0; u < 2; ++u) {
                int sj = cl[j + u * 4 + g];                    // 4-addr LDS broadcast
                uint4v v = xs4[((size_t)sj << 4) + l16];       // 16 B of the 256 B row
                a0 += lo_bf(v.x); a1 += hi_bf(v.x);
                a2 += lo_bf(v.y); a3 += hi_bf(v.y);
                a4 += lo_bf(v.z); a5 += hi_bf(v.z);
                a6 += lo_bf(v.w); a7 += hi_bf(v.w);
            }
        }
        // combine the 4 edge groups
        a0 += __shfl_xor(a0, 16, 64); a0 += __shfl_xor(a0, 32, 64);
        a1 += __shfl_xor(a1, 16, 64); a1 += __shfl_xor(a1, 32, 64);
        a2 += __shfl_xor(a2, 16, 64); a2 += __shfl_xor(a2, 32, 64);
        a3 += __shfl_xor(a3, 16, 64); a3 += __shfl_xor(a3, 32, 64);
        a4 += __shfl_xor(a4, 16, 64); a4 += __shfl_xor(a4, 32, 64);
        a5 += __shfl_xor(a5, 16, 64); a5 += __shfl_xor(a5, 32, 64);
        a6 += __shfl_xor(a6, 16, 64); a6 += __shfl_xor(a6, 32, 64);
        a7 += __shfl_xor(a7, 16, 64); a7 += __shfl_xor(a7, 32, 64);
        if (g == 0) {
            // self-loop + scale + bias + relu, write h2 row segment (16 B)
            uint4v vs = xs4[((size_t)node << 4) + l16];
            a0 += lo_bf(vs.x); a1 += hi_bf(vs.x);
            a2 += lo_bf(vs.y); a3 += hi_bf(vs.y);
            a4 += lo_bf(vs.z); a5 += hi_bf(vs.z);
            a6 += lo_bf(vs.w); a7 += hi_bf(vs.w);
            short8 o;
            o.s0 = f2bf(fmaxf(fmaf(a0, dv, bgA.x), 0.f));
            o.s1 = f2bf(fmaxf(fmaf(a1, dv, bgA.y), 0.f));
            o.s2 = f2bf(fmaxf(fmaf(a2, dv, bgA.z), 0.f));
            o.s3 = f2bf(fmaxf(fmaf(a3, dv, bgA.w), 0.f));
            o.s4 = f2bf(fmaxf(fmaf(a4, dv, bgB.x), 0.f));
            o.s5 = f2bf(fmaxf(fmaf(a5, dv, bgB.y), 0.f));
            o.s6 = f2bf(fmaxf(fmaf(a6, dv, bgB.z), 0.f));
            o.s7 = f2bf(fmaxf(fmaf(a7, dv, bgB.w), 0.f));
            *reinterpret_cast<short8*>(&h2_l[wave][ld - wave * 16][l16 * 8]) = o;
        }
    }
    __syncthreads();  // all waves done with csr_l; region A becomes hq_l
    short* hq_l = (short*)smemA;  // [4][16][264]

    // ---- phase 2: hq = relu(h2@W1+b1) -> LDS -> q = hq@W2 + b2 ----
    const int quad = lane >> 4;
    const int node0 = b * 64 + wave * 16;

    f32x4 acc[16] = {};
#pragma unroll
    for (int kc = 0; kc < 4; ++kc) {
        short8 xfrag = *reinterpret_cast<const short8*>(&h2_l[wave][l16][kc * 32 + quad * 8]);
#pragma unroll
        for (int t = 0; t < 16; ++t) {
            short8 wfrag = *reinterpret_cast<const short8*>(Wt1 + (size_t)(t * 16 + l16) * 128 + kc * 32 + quad * 8);
            acc[t] = __builtin_amdgcn_mfma_f32_16x16x32_bf16(wfrag, xfrag, acc[t], 0, 0, 0);
        }
    }
#pragma unroll
    for (int t = 0; t < 16; ++t) {
        short4v o;
#pragma unroll
        for (int r = 0; r < 4; ++r)
            ((short*)&o)[r] = f2bf(fmaxf(acc[t][r] + b1[t * 16 + quad * 4 + r], 0.f));
        *reinterpret_cast<short4v*>(&hq_l[(wave * 16 + l16) * 264 + t * 16 + quad * 4]) = o;
    }
    // wave-private tile: ds_write -> ds_read ordered by lgkmcnt

    f32x4 a2 = {};
#pragma unroll
    for (int kc = 0; kc < 8; ++kc) {
        short8 afrag = *reinterpret_cast<const short8*>(&hq_l[(wave * 16 + l16) * 264 + kc * 32 + quad * 8]);
        short8 bfrag = *reinterpret_cast<const short8*>(W2t + (size_t)l16 * 256 + kc * 32 + quad * 8);
        a2 = __builtin_amdgcn_mfma_f32_16x16x32_bf16(afrag, bfrag, a2, 0, 0, 0);
    }
    if (l16 < 10) {
        float bv = b2[l16];
#pragma unroll
        for (int r = 0; r < 4; ++r) {
            int nd = node0 + quad * 4 + r;
            if (nd < N_NODES) q[(size_t)nd * 10 + l16] = a2[r] + bv;
        }
    }
}

extern "C" void kernel_launch(void* const* d_in, const int* in_sizes, int n_in,
                              void* d_out, int out_size, void* d_ws, size_t ws_size,
                              hipStream_t stream) {
    const float* x     = (const float*)d_in[0];
    const int*   ei    = (const int*)d_in[1];
    const float* W_enc = (const float*)d_in[2];
    const float* b_enc = (const float*)d_in[3];
    const float* W_gcn = (const float*)d_in[4];
    const float* b_gcn = (const float*)d_in[5];
    const float* W1    = (const float*)d_in[6];
    const float* b1    = (const float*)d_in[7];
    const float* W2    = (const float*)d_in[8];
    const float* b2    = (const float*)d_in[9];
    float* q = (float*)d_out;

    const int E = in_sizes[1] / 2;
    const int* srcv = ei;
    const int* dstv = ei + E;

    // workspace layout (bytes)
    char* ws = (char*)d_ws;
    const size_t XSB = (size_t)(NB * 64) * 128 * sizeof(short);  // 25,608,192 (incl. pad rows)
    short* xs  = (short*)(ws);
    int*   part= (int*)  (ws + XSB);                             // 16,005,120
    char*  tail = ws + XSB + (size_t)NB * BCAP * sizeof(int);
    int*   bcr = (int*)(tail);                                   // 8 KB slot
    short* Wte = (short*)(tail + 8192);
    short* Wtg = (short*)(tail + 8192 + 32768);
    short* Wt1 = (short*)(tail + 8192 + 65536);
    short* W2t = (short*)(tail + 8192 + 131072);
    // end ~= 42 MB

    prep_kernel<<<279, 256, 0, stream>>>(W_enc, W_gcn, W1, W2, Wte, Wtg, Wt1, W2t, bcr);
    part_kernel<<<(E + CHUNK - 1) / CHUNK, 512, 0, stream>>>(srcv, dstv, bcr, part, E);
    gemmA_kernel<<<NB, 256, 0, stream>>>(x, Wte, Wtg, b_enc, bcr, part, xs);
    aggB_kernel<<<NB, 256, 0, stream>>>(xs, bcr, part, b_gcn, Wt1, W2t, b1, b2, q);
}